// Round 18
// baseline (118.872 us; speedup 1.0000x reference)
//
#include <hip/hip_runtime.h>
#include <hip/hip_bf16.h>

// Fused MHA: B=2, T=2048, C=1024, H=16, dh=64.
// cvt_xw -> qkv GEMM (both-bf16 reg-staged, XCD-tiled; V transposed via LDS epilogue)
// -> flash attention (512 uniform paired blocks, XCD-local, KVBLK=128 per iteration,
//    17 iters/block, 1-barrier dbuf, XOR-swizzled LDS, per-lane defer-max)
// -> cvt_wc -> out GEMM (both-bf16, XCD-tiled).
// ws (32 MiB): Qb | Kb | VtG | Ob; Wc_bf16 reuses Qb region after attn.
// d_out scratch: xb [0,8MB) + wqkvb [8,14MB), dead before gemm_out writes out.

typedef __attribute__((ext_vector_type(4))) float f32x4;
typedef __attribute__((ext_vector_type(4))) unsigned int u32x4;
typedef __attribute__((ext_vector_type(8))) __bf16 bf16x8;
typedef __attribute__((ext_vector_type(8))) unsigned short us8;
typedef __attribute__((ext_vector_type(4))) unsigned short us4;

#define LOG2E 1.4426950408889634f

__device__ __forceinline__ unsigned short f2bf(float f) {
    unsigned u = __builtin_bit_cast(unsigned, f);
    u += 0x7fffu + ((u >> 16) & 1u);   // round-to-nearest-even
    return (unsigned short)(u >> 16);
}

__device__ __forceinline__ unsigned cvt_pk_bf16(float lo, float hi) {
    unsigned r;
    asm("v_cvt_pk_bf16_f32 %0, %1, %2" : "=v"(r) : "v"(lo), "v"(hi));
    return r;
}

__device__ __forceinline__ f32x4 mfma16(us8 a, us8 b, f32x4 c) {
    return __builtin_amdgcn_mfma_f32_16x16x32_bf16(
        __builtin_bit_cast(bf16x8, a), __builtin_bit_cast(bf16x8, b), c, 0, 0, 0);
}

__global__ __launch_bounds__(256) void fill_sentinel(float* __restrict__ out, int n) {
    int i = blockIdx.x * 256 + threadIdx.x;
    if (i < n) out[i] = 12345.0f;
}

// ---- convert x + Wq|Wk|Wv fp32 -> bf16. 7168 blocks x 256 x 4.
__global__ __launch_bounds__(256) void cvt_xw(
    const float* __restrict__ x, const float* __restrict__ wq,
    const float* __restrict__ wk, const float* __restrict__ wv,
    unsigned short* __restrict__ xb, unsigned short* __restrict__ wqkvb) {
    long i = (long)(blockIdx.x * 256 + threadIdx.x) * 4;
    const float* src; unsigned short* dst; long off;
    if (i < 4194304L)      { src = x;  dst = xb;              off = i; }
    else if (i < 5242880L) { src = wq; dst = wqkvb;           off = i - 4194304L; }
    else if (i < 6291456L) { src = wk; dst = wqkvb + 1048576; off = i - 5242880L; }
    else                   { src = wv; dst = wqkvb + 2097152; off = i - 6291456L; }
    f32x4 v = *(const f32x4*)(src + off);
    us4 o = { f2bf(v[0]), f2bf(v[1]), f2bf(v[2]), f2bf(v[3]) };
    *(us4*)(dst + off) = o;
}

__global__ __launch_bounds__(256) void cvt_wc(const float* __restrict__ wc,
                                              unsigned short* __restrict__ wcb) {
    int idx = (blockIdx.x * 256 + threadIdx.x) * 4;
    f32x4 v = *(const f32x4*)(wc + idx);
    us4 o = { f2bf(v[0]), f2bf(v[1]), f2bf(v[2]), f2bf(v[3]) };
    *(us4*)(wcb + idx) = o;
}

// ---------------- both-bf16 reg-staged GEMM core ----------------
template <int MI>
__device__ __forceinline__ void gemm_core_bb(
    const unsigned short* __restrict__ A, const unsigned short* __restrict__ B,
    int K, int m0, int n0, unsigned short* As, unsigned short* Bs, f32x4 acc[MI][4]) {
    const int tid = threadIdx.x;
    const int lane = tid & 63, wid = tid >> 6;
    const int g = lane >> 4, s = lane & 15;
    const int wr = wid >> 1, wc = wid & 1;
#pragma unroll
    for (int mi = 0; mi < MI; mi++)
#pragma unroll
        for (int ni = 0; ni < 4; ni++) acc[mi][ni] = (f32x4){0.f, 0.f, 0.f, 0.f};
    const int row = tid >> 3, col = (tid & 7) * 8;
    for (int k0 = 0; k0 < K; k0 += 64) {
        us8 av[MI], bv[4];
#pragma unroll
        for (int p = 0; p < MI; p++)
            av[p] = *(const us8*)(A + (size_t)(m0 + row + p * 32) * K + k0 + col);
#pragma unroll
        for (int p = 0; p < 4; p++)
            bv[p] = *(const us8*)(B + (size_t)(n0 + row + p * 32) * K + k0 + col);
        __syncthreads();
#pragma unroll
        for (int p = 0; p < MI; p++)
            *(us8*)(As + (row + p * 32) * 72 + col) = av[p];
#pragma unroll
        for (int p = 0; p < 4; p++)
            *(us8*)(Bs + (row + p * 32) * 72 + col) = bv[p];
        __syncthreads();
#pragma unroll
        for (int kk = 0; kk < 2; kk++) {
            us8 af[MI], bf[4];
#pragma unroll
            for (int mi = 0; mi < MI; mi++)
                af[mi] = *(const us8*)(As + (wr * (MI * 16) + mi * 16 + s) * 72 + kk * 32 + g * 8);
#pragma unroll
            for (int ni = 0; ni < 4; ni++)
                bf[ni] = *(const us8*)(Bs + (wc * 64 + ni * 16 + s) * 72 + kk * 32 + g * 8);
#pragma unroll
            for (int mi = 0; mi < MI; mi++)
#pragma unroll
                for (int ni = 0; ni < 4; ni++)
                    acc[mi][ni] = mfma16(af[mi], bf[ni], acc[mi][ni]);
        }
    }
}

// ---------------- QKV projection (XCD-tiled); V transposed via LDS epilogue ----------------
__global__ __launch_bounds__(256) void gemm_qkv(
    const unsigned short* __restrict__ X, const unsigned short* __restrict__ Wb,
    unsigned short* __restrict__ Qb, unsigned short* __restrict__ Kb,
    unsigned short* __restrict__ VtG) {
    __shared__ unsigned short S[18432];   // As[128*72] | Bs[128*72]; V reuse: T[128][136]=17408
    unsigned short* As = S;
    unsigned short* Bs = S + 9216;
    const int bid = blockIdx.x;
    const int xcd = bid & 7, idx = bid >> 3;               // idx 0..95
    const int bm  = (xcd & 3) * 8 + (idx & 7);             // 0..31
    const int bnl = (xcd >> 2) * 12 + (idx >> 3);          // 0..23
    const int m0 = bm * 128;
    const int which = bnl >> 3;                            // 0:Q 1:K 2:V
    const int n0 = (bnl & 7) * 128;
    const unsigned short* W = Wb + (size_t)which * 1048576;
    f32x4 acc[4][4];
    gemm_core_bb<4>(X, W, 1024, m0, n0, As, Bs, acc);
    const int tid = threadIdx.x, lane = tid & 63, wid = tid >> 6;
    const int g = lane >> 4, s = lane & 15, wr = wid >> 1, wc = wid & 1;
    if (which < 2) {
        unsigned short* dst = which == 0 ? Qb : Kb;
        const float scale = which == 0 ? 0.125f : 1.0f;
#pragma unroll
        for (int mi = 0; mi < 4; mi++)
#pragma unroll
            for (int ni = 0; ni < 4; ni++) {
                int n1 = n0 + wc * 64 + ni * 16 + s;
                int hh = n1 >> 6, dd = n1 & 63;
#pragma unroll
                for (int r = 0; r < 4; r++) {
                    int mg = m0 + wr * 64 + mi * 16 + 4 * g + r;
                    int bb = mg >> 11, tt = mg & 2047;
                    dst[((size_t)(bb * 16 + hh) * 2048 + tt) * 64 + dd] = f2bf(acc[mi][ni][r] * scale);
                }
            }
    } else {
        __syncthreads();
        unsigned* T32 = (unsigned*)S;   // T[128][136] shorts = [128][68] dwords
#pragma unroll
        for (int mi = 0; mi < 4; mi++)
#pragma unroll
            for (int ni = 0; ni < 4; ni++) {
                int nl = wc * 64 + ni * 16 + s;
                int mlh = ((wr * 64 + mi * 16) >> 1) + 2 * g;
                T32[nl * 68 + mlh]     = cvt_pk_bf16(acc[mi][ni][0], acc[mi][ni][1]);
                T32[nl * 68 + mlh + 1] = cvt_pk_bf16(acc[mi][ni][2], acc[mi][ni][3]);
            }
        __syncthreads();
        const int row = tid >> 4, col8 = (tid & 15) * 8;
        const int bb = m0 >> 11, tt0 = m0 & 2047;
#pragma unroll
        for (int p = 0; p < 8; p++) {
            int nl = row + 16 * p;
            int n1 = n0 + nl, hh = n1 >> 6, dd = n1 & 63;
            us8 v = *(const us8*)(S + nl * 136 + col8);
            *(us8*)(VtG + ((size_t)(bb * 16 + hh) * 64 + dd) * 2048 + tt0 + col8) = v;
        }
    }
}

// ---------------- flash attention (causal), KVBLK=128, 17 uniform iters ----------------
// bh = bid&31 (XCD-local heads), i = bid>>5 (0..15). Tiles A=i, B=31-i.
// nA = ceil((i+1)/2) 128-row iters for A, nB = 17-nA for B (uniform 17 total);
// odd remainders are fully-masked half-tiles (safe: sub0 always has real values).
// K LDS [128][64] rows 128B, Vt LDS [64][128] rows 256B; XOR swizzle (row&7)<<4.
#define ATTN_EPILOGUE(QB0, OA, LP)                                              \
    {                                                                           \
        float lf = (LP);                                                        \
        lf += __shfl_xor(lf, 16);                                               \
        lf += __shfl_xor(lf, 32);                                               \
        float li[4];                                                            \
        _Pragma("unroll") for (int r = 0; r < 4; r++)                           \
            li[r] = __shfl(lf, 4 * g + r, 64);                                  \
        _Pragma("unroll") for (int db = 0; db < 4; db++)                        \
            _Pragma("unroll") for (int r = 0; r < 4; r++) {                     \
                int qq = (QB0) + 4 * g + r;                                     \
                float v = (OA)[db][r] / li[r];                                  \
                Ob[((size_t)(b * 2048) + qq) * 1024 + h * 64 + db * 16 + s] = f2bf(v); \
            }                                                                   \
    }

__global__ __launch_bounds__(256, 2) void attn(
    const unsigned short* __restrict__ Qb, const unsigned short* __restrict__ Kb,
    const unsigned short* __restrict__ VtG, unsigned short* __restrict__ Ob) {
    __shared__ unsigned short Ks[2][128 * 64];  // [k][d], swizzled
    __shared__ unsigned short Vt[2][64 * 128];  // [d][t], swizzled
    const int bh = blockIdx.x & 31, i = blockIdx.x >> 5;   // i in 0..15
    const int b = bh >> 4, h = bh & 15;
    const unsigned short* Qp = Qb + (size_t)bh * 2048 * 64;
    const unsigned short* Kp = Kb + (size_t)bh * 2048 * 64;
    const unsigned short* Vp = VtG + (size_t)bh * 64 * 2048;   // [d][t]
    const int tid = threadIdx.x, lane = tid & 63, wid = tid >> 6;
    const int g = lane >> 4, s = lane & 15;
    const int qbA = i * 64 + wid * 16;          // tile A wave q-base
    const int qbB = (31 - i) * 64 + wid * 16;   // tile B wave q-base
    const int qgA = qbA + s, qgB = qbB + s;
    us8 qfA[2], qfB[2];
    qfA[0] = *(const us8*)(Qp + (size_t)qgA * 64 + g * 8);
    qfA[1] = *(const us8*)(Qp + (size_t)qgA * 64 + 32 + g * 8);
    qfB[0] = *(const us8*)(Qp + (size_t)qgB * 64 + g * 8);
    qfB[1] = *(const us8*)(Qp + (size_t)qgB * 64 + 32 + g * 8);
    float m_run = -3.0e38f, l_part = 0.f;
    f32x4 o_acc[4];
#pragma unroll
    for (int db = 0; db < 4; db++) o_acc[db] = (f32x4){0.f, 0.f, 0.f, 0.f};
    const int nA = (i + 2) >> 1;               // A iterations (17 total, uniform)
    const int krow = tid >> 3, kcolb = (tid & 7) * 16;
    const int vd = tid >> 2, vcb = (tid & 3) * 16;
    const int swl = (s & 7) << 4;
    const int vsw = (vd & 7) << 4;
    auto tb = [&](int t) { return (t < nA ? t : t - nA) * 128; };
    us8 kpre[4], vpre[4];
    auto loadpre = [&](int base) {
#pragma unroll
        for (int p = 0; p < 4; p++) {
            kpre[p] = *(const us8*)((const char*)Kp + (size_t)(base + krow + 32 * p) * 128 + kcolb);
            vpre[p] = *(const us8*)((const char*)Vp + (size_t)vd * 4096 + base * 2 + vcb + p * 64);
        }
    };
    auto writebuf = [&](int bi) {
#pragma unroll
        for (int p = 0; p < 4; p++) {
            int r = krow + 32 * p;
            *(us8*)((char*)&Ks[bi][0] + r * 128 + (kcolb ^ ((r & 7) << 4))) = kpre[p];
            *(us8*)((char*)&Vt[bi][0] + vd * 256 + ((vcb + p * 64) ^ vsw)) = vpre[p];
        }
    };
    loadpre(0);
    writebuf(0);
    loadpre(tb(1));
    int cur = 0;
    for (int it = 0; it < 17; ++it) {
        __syncthreads();   // buf[cur] writes visible; prior reads of buf[cur^1] done
        if (it < 16) {
            writebuf(cur ^ 1);
            if (it < 15) loadpre(tb(it + 2));
        }
        if (it == nA) {    // tile A finished: emit + reset stats
            ATTN_EPILOGUE(qbA, o_acc, l_part);
            m_run = -3.0e38f; l_part = 0.f;
#pragma unroll
            for (int db = 0; db < 4; db++) o_acc[db] = (f32x4){0.f, 0.f, 0.f, 0.f};
        }
        const bool isA = it < nA;
        const int kvb = tb(it);
        const int qg = isA ? qgA : qgB;
        const int qbW = isA ? qbA : qbB;
        const us8* qf = isA ? qfA : qfB;
        const char* Kc = (const char*)&Ks[cur][0];
        const char* Vc = (const char*)&Vt[cur][0];
        float sf[2][4][4];
        __builtin_amdgcn_s_setprio(1);
#pragma unroll
        for (int sub = 0; sub < 2; sub++)
#pragma unroll
            for (int f = 0; f < 4; f++) {
                const char* krp = Kc + (sub * 64 + f * 16 + s) * 128;
                us8 k0v = *(const us8*)(krp + ((g * 16) ^ swl));
                us8 k1v = *(const us8*)(krp + ((64 + g * 16) ^ swl));
                f32x4 a = (f32x4){0.f, 0.f, 0.f, 0.f};
                a = mfma16(k0v, qf[0], a);
                a = mfma16(k1v, qf[1], a);
#pragma unroll
                for (int r = 0; r < 4; r++) sf[sub][f][r] = a[r];
            }
        __builtin_amdgcn_s_setprio(0);
#pragma unroll
        for (int sub = 0; sub < 2; sub++) {
            const int kv0 = kvb + sub * 64;
            if (kv0 + 63 > qbW) {   // wave-uniform gate; per-lane causal mask
#pragma unroll
                for (int f = 0; f < 4; f++)
#pragma unroll
                    for (int r = 0; r < 4; r++)
                        if (kv0 + f * 16 + 4 * g + r > qg) sf[sub][f][r] = -3.0e38f;
            }
        }
        // per-lane defer-max over all 32 values
        float mt = -3.0e38f;
#pragma unroll
        for (int sub = 0; sub < 2; sub++)
#pragma unroll
            for (int f = 0; f < 4; f++)
#pragma unroll
                for (int r = 0; r < 4; r++) mt = fmaxf(mt, sf[sub][f][r]);
        if (!__all(mt - m_run <= 8.0f)) {   // rare: reduce + rescale
            mt = fmaxf(mt, __shfl_xor(mt, 16));
            mt = fmaxf(mt, __shfl_xor(mt, 32));
            float mnew = fmaxf(m_run, mt);
            float alpha = __builtin_amdgcn_exp2f((m_run - mnew) * LOG2E);
            l_part *= alpha;
            float al[4];
#pragma unroll
            for (int r = 0; r < 4; r++) al[r] = __shfl(alpha, 4 * g + r, 64);
#pragma unroll
            for (int db = 0; db < 4; db++)
#pragma unroll
                for (int r = 0; r < 4; r++) o_acc[db][r] *= al[r];
            m_run = mnew;
        }
        float psum = 0.f;
#pragma unroll
        for (int sub = 0; sub < 2; sub++)
#pragma unroll
            for (int f = 0; f < 4; f++)
#pragma unroll
                for (int r = 0; r < 4; r++) {
                    float p = __builtin_amdgcn_exp2f((sf[sub][f][r] - m_run) * LOG2E);
                    sf[sub][f][r] = p;
                    psum += p;
                }
        l_part += psum;   // per-lane partial; reduced once in epilogue
        // per sub-tile: packed redistribute + PV
#pragma unroll
        for (int sub = 0; sub < 2; sub++) {
            unsigned pk[4][2];
#pragma unroll
            for (int f = 0; f < 4; f++)
#pragma unroll
                for (int hh2 = 0; hh2 < 2; hh2++)
                    pk[f][hh2] = cvt_pk_bf16(sf[sub][f][2 * hh2], sf[sub][f][2 * hh2 + 1]);
            const int srcA = 32 * (g & 1) + s, srcB = srcA + 16;
            const bool ghi = g >= 2;
            us8 pa[2];
#pragma unroll
            for (int kk = 0; kk < 2; kk++) {
                unsigned e0 = __shfl(pk[kk * 2][0], srcA, 64);
                unsigned e1 = __shfl(pk[kk * 2][1], srcA, 64);
                unsigned e2 = __shfl(pk[kk * 2][0], srcB, 64);
                unsigned e3 = __shfl(pk[kk * 2][1], srcB, 64);
                unsigned o0 = __shfl(pk[kk * 2 + 1][0], srcA, 64);
                unsigned o1 = __shfl(pk[kk * 2 + 1][1], srcA, 64);
                unsigned o2 = __shfl(pk[kk * 2 + 1][0], srcB, 64);
                unsigned o3 = __shfl(pk[kk * 2 + 1][1], srcB, 64);
                u32x4 dw = { ghi ? o0 : e0, ghi ? o1 : e1, ghi ? o2 : e2, ghi ? o3 : e3 };
                pa[kk] = __builtin_bit_cast(us8, dw);
            }
            __builtin_amdgcn_s_setprio(1);
#pragma unroll
            for (int db = 0; db < 4; db++) {
                const char* vrow = Vc + (db * 16 + s) * 256;
                us8 vf0 = *(const us8*)(vrow + ((sub * 128 + g * 16) ^ swl));
                o_acc[db] = mfma16(pa[0], vf0, o_acc[db]);
                us8 vf1 = *(const us8*)(vrow + ((sub * 128 + 64 + g * 16) ^ swl));
                o_acc[db] = mfma16(pa[1], vf1, o_acc[db]);
            }
            __builtin_amdgcn_s_setprio(0);
        }
        cur ^= 1;
    }
    ATTN_EPILOGUE(qbB, o_acc, l_part);
}

// ---------------- output projection: Ob x Wc_bf16^T + bc, XCD-tiled 64x128 ----------------
__global__ __launch_bounds__(256) void gemm_out(
    const unsigned short* __restrict__ O, const unsigned short* __restrict__ Wcb,
    const float* __restrict__ bc, float* __restrict__ out) {
    __shared__ unsigned short As[64 * 72];
    __shared__ unsigned short Bs[128 * 72];
    const int bid = blockIdx.x;
    const int xcd = bid & 7, idx = bid >> 3;     // idx 0..63
    const int bm = xcd * 8 + (idx & 7);          // 0..63
    const int bn = idx >> 3;                     // 0..7
    const int m0 = bm * 64, n0 = bn * 128;
    f32x4 acc[2][4];
    gemm_core_bb<2>(O, Wcb, 1024, m0, n0, As, Bs, acc);
    const int lane = threadIdx.x & 63, wid = threadIdx.x >> 6;
    const int g = lane >> 4, s = lane & 15, wr = wid >> 1, wc = wid & 1;
#pragma unroll
    for (int mi = 0; mi < 2; mi++)
#pragma unroll
        for (int ni = 0; ni < 4; ni++) {
            int ng = n0 + wc * 64 + ni * 16 + s;
            float bias = bc[ng];
#pragma unroll
            for (int r = 0; r < 4; r++) {
                int mg = m0 + wr * 32 + mi * 16 + 4 * g + r;
                out[(size_t)mg * 1024 + ng] = acc[mi][ni][r] + bias;
            }
        }
}

extern "C" void kernel_launch(void* const* d_in, const int* in_sizes, int n_in,
                              void* d_out, int out_size, void* d_ws, size_t ws_size,
                              hipStream_t stream) {
    const float* x  = (const float*)d_in[0];
    const float* Wq = (const float*)d_in[1];
    const float* Wk = (const float*)d_in[2];
    const float* Wv = (const float*)d_in[3];
    const float* Wc = (const float*)d_in[4];
    const float* bc = (const float*)d_in[5];
    float* out = (float*)d_out;

    if (ws_size < 33554432) {
        fill_sentinel<<<(out_size + 255) / 256, 256, 0, stream>>>(out, out_size);
        return;
    }
    char* w = (char*)d_ws;
    unsigned short* Qb  = (unsigned short*)(w);
    unsigned short* Kb  = (unsigned short*)(w + 8388608);
    unsigned short* VtG = (unsigned short*)(w + 16777216);   // [bh][d][t]
    unsigned short* Ob  = (unsigned short*)(w + 25165824);
    unsigned short* Wcb = (unsigned short*)(w);              // reuses Qb region after attn
    unsigned short* xb    = (unsigned short*)d_out;
    unsigned short* wqkvb = (unsigned short*)((char*)d_out + 8388608);

    cvt_xw<<<7168, 256, 0, stream>>>(x, Wq, Wk, Wv, xb, wqkvb);
    gemm_qkv<<<768, 256, 0, stream>>>(xb, wqkvb, Qb, Kb, VtG);
    attn<<<512, 256, 0, stream>>>(Qb, Kb, VtG, Ob);
    cvt_wc<<<1024, 256, 0, stream>>>(Wc, Wcb);
    gemm_out<<<512, 256, 0, stream>>>(Ob, Wcb, bc, out);
}

// Round 19
// 118.044 us; speedup vs baseline: 1.0070x; 1.0070x over previous
//
#include <hip/hip_runtime.h>
#include <hip/hip_bf16.h>

// Fused MHA: B=2, T=2048, C=1024, H=16, dh=64.  (R17 best configuration, reverted)
// cvt_xw -> qkv GEMM (both-bf16 reg-staged, XCD-tiled; V transposed via LDS epilogue)
// -> flash attention (512 uniform paired blocks, XCD-local, 1-barrier dbuf,
//    XOR-swizzled [64][64] K/V LDS (conflict-free), per-lane defer-max)
// -> cvt_wc -> out GEMM (both-bf16, XCD-tiled).
// ws (32 MiB): Qb | Kb | VtG | Ob; Wc_bf16 reuses Qb region after attn.
// d_out scratch: xb [0,8MB) + wqkvb [8,14MB), dead before gemm_out writes out.

typedef __attribute__((ext_vector_type(4))) float f32x4;
typedef __attribute__((ext_vector_type(4))) unsigned int u32x4;
typedef __attribute__((ext_vector_type(8))) __bf16 bf16x8;
typedef __attribute__((ext_vector_type(8))) unsigned short us8;
typedef __attribute__((ext_vector_type(4))) unsigned short us4;

#define LOG2E 1.4426950408889634f

__device__ __forceinline__ unsigned short f2bf(float f) {
    unsigned u = __builtin_bit_cast(unsigned, f);
    u += 0x7fffu + ((u >> 16) & 1u);   // round-to-nearest-even
    return (unsigned short)(u >> 16);
}

__device__ __forceinline__ unsigned cvt_pk_bf16(float lo, float hi) {
    unsigned r;
    asm("v_cvt_pk_bf16_f32 %0, %1, %2" : "=v"(r) : "v"(lo), "v"(hi));
    return r;
}

__device__ __forceinline__ f32x4 mfma16(us8 a, us8 b, f32x4 c) {
    return __builtin_amdgcn_mfma_f32_16x16x32_bf16(
        __builtin_bit_cast(bf16x8, a), __builtin_bit_cast(bf16x8, b), c, 0, 0, 0);
}

__global__ __launch_bounds__(256) void fill_sentinel(float* __restrict__ out, int n) {
    int i = blockIdx.x * 256 + threadIdx.x;
    if (i < n) out[i] = 12345.0f;
}

// ---- convert x + Wq|Wk|Wv fp32 -> bf16. 7168 blocks x 256 x 4.
__global__ __launch_bounds__(256) void cvt_xw(
    const float* __restrict__ x, const float* __restrict__ wq,
    const float* __restrict__ wk, const float* __restrict__ wv,
    unsigned short* __restrict__ xb, unsigned short* __restrict__ wqkvb) {
    long i = (long)(blockIdx.x * 256 + threadIdx.x) * 4;
    const float* src; unsigned short* dst; long off;
    if (i < 4194304L)      { src = x;  dst = xb;              off = i; }
    else if (i < 5242880L) { src = wq; dst = wqkvb;           off = i - 4194304L; }
    else if (i < 6291456L) { src = wk; dst = wqkvb + 1048576; off = i - 5242880L; }
    else                   { src = wv; dst = wqkvb + 2097152; off = i - 6291456L; }
    f32x4 v = *(const f32x4*)(src + off);
    us4 o = { f2bf(v[0]), f2bf(v[1]), f2bf(v[2]), f2bf(v[3]) };
    *(us4*)(dst + off) = o;
}

__global__ __launch_bounds__(256) void cvt_wc(const float* __restrict__ wc,
                                              unsigned short* __restrict__ wcb) {
    int idx = (blockIdx.x * 256 + threadIdx.x) * 4;
    f32x4 v = *(const f32x4*)(wc + idx);
    us4 o = { f2bf(v[0]), f2bf(v[1]), f2bf(v[2]), f2bf(v[3]) };
    *(us4*)(wcb + idx) = o;
}

// ---------------- both-bf16 reg-staged GEMM core ----------------
template <int MI>
__device__ __forceinline__ void gemm_core_bb(
    const unsigned short* __restrict__ A, const unsigned short* __restrict__ B,
    int K, int m0, int n0, unsigned short* As, unsigned short* Bs, f32x4 acc[MI][4]) {
    const int tid = threadIdx.x;
    const int lane = tid & 63, wid = tid >> 6;
    const int g = lane >> 4, s = lane & 15;
    const int wr = wid >> 1, wc = wid & 1;
#pragma unroll
    for (int mi = 0; mi < MI; mi++)
#pragma unroll
        for (int ni = 0; ni < 4; ni++) acc[mi][ni] = (f32x4){0.f, 0.f, 0.f, 0.f};
    const int row = tid >> 3, col = (tid & 7) * 8;
    for (int k0 = 0; k0 < K; k0 += 64) {
        us8 av[MI], bv[4];
#pragma unroll
        for (int p = 0; p < MI; p++)
            av[p] = *(const us8*)(A + (size_t)(m0 + row + p * 32) * K + k0 + col);
#pragma unroll
        for (int p = 0; p < 4; p++)
            bv[p] = *(const us8*)(B + (size_t)(n0 + row + p * 32) * K + k0 + col);
        __syncthreads();
#pragma unroll
        for (int p = 0; p < MI; p++)
            *(us8*)(As + (row + p * 32) * 72 + col) = av[p];
#pragma unroll
        for (int p = 0; p < 4; p++)
            *(us8*)(Bs + (row + p * 32) * 72 + col) = bv[p];
        __syncthreads();
#pragma unroll
        for (int kk = 0; kk < 2; kk++) {
            us8 af[MI], bf[4];
#pragma unroll
            for (int mi = 0; mi < MI; mi++)
                af[mi] = *(const us8*)(As + (wr * (MI * 16) + mi * 16 + s) * 72 + kk * 32 + g * 8);
#pragma unroll
            for (int ni = 0; ni < 4; ni++)
                bf[ni] = *(const us8*)(Bs + (wc * 64 + ni * 16 + s) * 72 + kk * 32 + g * 8);
#pragma unroll
            for (int mi = 0; mi < MI; mi++)
#pragma unroll
                for (int ni = 0; ni < 4; ni++)
                    acc[mi][ni] = mfma16(af[mi], bf[ni], acc[mi][ni]);
        }
    }
}

// ---------------- QKV projection (XCD-tiled); V transposed via LDS epilogue ----------------
__global__ __launch_bounds__(256) void gemm_qkv(
    const unsigned short* __restrict__ X, const unsigned short* __restrict__ Wb,
    unsigned short* __restrict__ Qb, unsigned short* __restrict__ Kb,
    unsigned short* __restrict__ VtG) {
    __shared__ unsigned short S[18432];   // As[128*72] | Bs[128*72]; V reuse: T[128][136]=17408
    unsigned short* As = S;
    unsigned short* Bs = S + 9216;
    const int bid = blockIdx.x;
    const int xcd = bid & 7, idx = bid >> 3;               // idx 0..95
    const int bm  = (xcd & 3) * 8 + (idx & 7);             // 0..31
    const int bnl = (xcd >> 2) * 12 + (idx >> 3);          // 0..23
    const int m0 = bm * 128;
    const int which = bnl >> 3;                            // 0:Q 1:K 2:V
    const int n0 = (bnl & 7) * 128;
    const unsigned short* W = Wb + (size_t)which * 1048576;
    f32x4 acc[4][4];
    gemm_core_bb<4>(X, W, 1024, m0, n0, As, Bs, acc);
    const int tid = threadIdx.x, lane = tid & 63, wid = tid >> 6;
    const int g = lane >> 4, s = lane & 15, wr = wid >> 1, wc = wid & 1;
    if (which < 2) {
        unsigned short* dst = which == 0 ? Qb : Kb;
        const float scale = which == 0 ? 0.125f : 1.0f;
#pragma unroll
        for (int mi = 0; mi < 4; mi++)
#pragma unroll
            for (int ni = 0; ni < 4; ni++) {
                int n1 = n0 + wc * 64 + ni * 16 + s;
                int hh = n1 >> 6, dd = n1 & 63;
#pragma unroll
                for (int r = 0; r < 4; r++) {
                    int mg = m0 + wr * 64 + mi * 16 + 4 * g + r;
                    int bb = mg >> 11, tt = mg & 2047;
                    dst[((size_t)(bb * 16 + hh) * 2048 + tt) * 64 + dd] = f2bf(acc[mi][ni][r] * scale);
                }
            }
    } else {
        __syncthreads();
        unsigned* T32 = (unsigned*)S;   // T[128][136] shorts = [128][68] dwords
#pragma unroll
        for (int mi = 0; mi < 4; mi++)
#pragma unroll
            for (int ni = 0; ni < 4; ni++) {
                int nl = wc * 64 + ni * 16 + s;
                int mlh = ((wr * 64 + mi * 16) >> 1) + 2 * g;
                T32[nl * 68 + mlh]     = cvt_pk_bf16(acc[mi][ni][0], acc[mi][ni][1]);
                T32[nl * 68 + mlh + 1] = cvt_pk_bf16(acc[mi][ni][2], acc[mi][ni][3]);
            }
        __syncthreads();
        const int row = tid >> 4, col8 = (tid & 15) * 8;
        const int bb = m0 >> 11, tt0 = m0 & 2047;
#pragma unroll
        for (int p = 0; p < 8; p++) {
            int nl = row + 16 * p;
            int n1 = n0 + nl, hh = n1 >> 6, dd = n1 & 63;
            us8 v = *(const us8*)(S + nl * 136 + col8);
            *(us8*)(VtG + ((size_t)(bb * 16 + hh) * 64 + dd) * 2048 + tt0 + col8) = v;
        }
    }
}

// ---------------- flash attention (causal), 512 uniform paired blocks, XCD-local ----------------
// bh = bid&31, i = bid>>5 (0..15). Tile A=i (iters 0..i) then B=31-i: 33 iters/block.
// K/V LDS: unpadded [64][64] shorts (128B rows = exact bank wrap) with XOR swizzle
// byte ^= (row&7)<<4  -> staging writes conflict-free, frag reads 2-way (free).
// Per-lane defer-max; l kept per-lane, reduced in epilogue. 1-barrier dbuf.
#define ATTN_EPILOGUE(QB0, OA, LP)                                              \
    {                                                                           \
        float lf = (LP);                                                        \
        lf += __shfl_xor(lf, 16);                                               \
        lf += __shfl_xor(lf, 32);                                               \
        float li[4];                                                            \
        _Pragma("unroll") for (int r = 0; r < 4; r++)                           \
            li[r] = __shfl(lf, 4 * g + r, 64);                                  \
        _Pragma("unroll") for (int db = 0; db < 4; db++)                        \
            _Pragma("unroll") for (int r = 0; r < 4; r++) {                     \
                int qq = (QB0) + 4 * g + r;                                     \
                float v = (OA)[db][r] / li[r];                                  \
                Ob[((size_t)(b * 2048) + qq) * 1024 + h * 64 + db * 16 + s] = f2bf(v); \
            }                                                                   \
    }

__global__ __launch_bounds__(256) void attn(
    const unsigned short* __restrict__ Qb, const unsigned short* __restrict__ Kb,
    const unsigned short* __restrict__ VtG, unsigned short* __restrict__ Ob) {
    __shared__ unsigned short Ks[2][64 * 64];  // [k][d], XOR-swizzled
    __shared__ unsigned short Vt[2][64 * 64];  // [d][k], XOR-swizzled
    const int bh = blockIdx.x & 31, i = blockIdx.x >> 5;   // i in 0..15
    const int b = bh >> 4, h = bh & 15;
    const unsigned short* Qp = Qb + (size_t)bh * 2048 * 64;
    const unsigned short* Kp = Kb + (size_t)bh * 2048 * 64;
    const unsigned short* Vp = VtG + (size_t)bh * 64 * 2048;   // [d][t]
    const int tid = threadIdx.x, lane = tid & 63, wid = tid >> 6;
    const int g = lane >> 4, s = lane & 15;
    const int qbA = i * 64 + wid * 16;          // tile A
    const int qbB = (31 - i) * 64 + wid * 16;   // tile B
    const int qgA = qbA + s, qgB = qbB + s;
    us8 qfA[2], qfB[2];
    qfA[0] = *(const us8*)(Qp + (size_t)qgA * 64 + g * 8);
    qfA[1] = *(const us8*)(Qp + (size_t)qgA * 64 + 32 + g * 8);
    qfB[0] = *(const us8*)(Qp + (size_t)qgB * 64 + g * 8);
    qfB[1] = *(const us8*)(Qp + (size_t)qgB * 64 + 32 + g * 8);
    float m_run = -3.0e38f, l_part = 0.f;
    f32x4 o_acc[4];
#pragma unroll
    for (int db = 0; db < 4; db++) o_acc[db] = (f32x4){0.f, 0.f, 0.f, 0.f};
    const int srow = tid >> 3;                 // 0..31
    const int scolb = (tid & 7) * 16;          // byte col within 128B row
    const int swl = (s & 7) << 4;              // read-side XOR (row&7 == s&7)
    auto tileoff = [&](int jj) { return (jj <= i ? jj : jj - i - 1) * 64; };
    us8 kpre[2], vpre[2];
    // stage tile 0 directly (swizzled write: byte = row*128 + (colb ^ ((row&7)<<4)))
#pragma unroll
    for (int p = 0; p < 2; p++) {
        kpre[p] = *(const us8*)((const char*)Kp + (size_t)(srow + 32 * p) * 128 + scolb);
        vpre[p] = *(const us8*)((const char*)Vp + (size_t)(srow + 32 * p) * 4096 + scolb);
    }
#pragma unroll
    for (int p = 0; p < 2; p++) {
        int row = srow + 32 * p;
        int sw = scolb ^ ((row & 7) << 4);
        *(us8*)((char*)&Ks[0][0] + row * 128 + sw) = kpre[p];
        *(us8*)((char*)&Vt[0][0] + row * 128 + sw) = vpre[p];
    }
    {   // prefetch tile 1
        const int nk = tileoff(1);
#pragma unroll
        for (int p = 0; p < 2; p++) {
            kpre[p] = *(const us8*)((const char*)Kp + (size_t)(nk + srow + 32 * p) * 128 + scolb);
            vpre[p] = *(const us8*)((const char*)Vp + (size_t)(srow + 32 * p) * 4096 + nk * 2 + scolb);
        }
    }
    int cur = 0;
    for (int it = 0; it <= 32; ++it) {
        __syncthreads();   // buf[cur] writes visible; prior reads of buf[cur^1] done
        if (it < 32) {     // stage tile it+1 into the other buffer
#pragma unroll
            for (int p = 0; p < 2; p++) {
                int row = srow + 32 * p;
                int sw = scolb ^ ((row & 7) << 4);
                *(us8*)((char*)&Ks[cur ^ 1][0] + row * 128 + sw) = kpre[p];
                *(us8*)((char*)&Vt[cur ^ 1][0] + row * 128 + sw) = vpre[p];
            }
            if (it < 31) {   // prefetch tile it+2
                const int nk = tileoff(it + 2);
#pragma unroll
                for (int p = 0; p < 2; p++) {
                    kpre[p] = *(const us8*)((const char*)Kp + (size_t)(nk + srow + 32 * p) * 128 + scolb);
                    vpre[p] = *(const us8*)((const char*)Vp + (size_t)(srow + 32 * p) * 4096 + nk * 2 + scolb);
                }
            }
        }
        if (it == i + 1) {   // tile A finished: emit + reset stats
            ATTN_EPILOGUE(qbA, o_acc, l_part);
            m_run = -3.0e38f; l_part = 0.f;
#pragma unroll
            for (int db = 0; db < 4; db++) o_acc[db] = (f32x4){0.f, 0.f, 0.f, 0.f};
        }
        const bool qsel = it > i;
        const int kv0 = tileoff(it);
        const int qg = qsel ? qgB : qgA;
        const us8* qf = qsel ? qfB : qfA;
        const char* Kc = (const char*)&Ks[cur][0];
        const char* Vc = (const char*)&Vt[cur][0];
        float sf[4][4];
        __builtin_amdgcn_s_setprio(1);
#pragma unroll
        for (int f = 0; f < 4; f++) {
            f32x4 a = (f32x4){0.f, 0.f, 0.f, 0.f};
            const char* krow = Kc + (f * 16 + s) * 128;
            us8 k0v = *(const us8*)(krow + ((g * 16) ^ swl));
            us8 k1v = *(const us8*)(krow + ((64 + g * 16) ^ swl));
            a = mfma16(k0v, qf[0], a);
            a = mfma16(k1v, qf[1], a);
#pragma unroll
            for (int r = 0; r < 4; r++) sf[f][r] = a[r];
        }
        __builtin_amdgcn_s_setprio(0);
        const bool diag = qsel ? (it == 32) : (it == i);
        if (diag) {   // diagonal tile: mask k > q
#pragma unroll
            for (int f = 0; f < 4; f++)
#pragma unroll
                for (int r = 0; r < 4; r++)
                    if (kv0 + f * 16 + 4 * g + r > qg) sf[f][r] = -3.0e38f;
        }
        // per-lane defer-max
        float mt = -3.0e38f;
#pragma unroll
        for (int f = 0; f < 4; f++)
#pragma unroll
            for (int r = 0; r < 4; r++) mt = fmaxf(mt, sf[f][r]);
        if (!__all(mt - m_run <= 8.0f)) {   // rare: reduce + rescale
            mt = fmaxf(mt, __shfl_xor(mt, 16));
            mt = fmaxf(mt, __shfl_xor(mt, 32));
            float mnew = fmaxf(m_run, mt);
            float alpha = __builtin_amdgcn_exp2f((m_run - mnew) * LOG2E);
            l_part *= alpha;
            float al[4];
#pragma unroll
            for (int r = 0; r < 4; r++) al[r] = __shfl(alpha, 4 * g + r, 64);
#pragma unroll
            for (int db = 0; db < 4; db++)
#pragma unroll
                for (int r = 0; r < 4; r++) o_acc[db][r] *= al[r];
            m_run = mnew;
        }
        float psum = 0.f;
#pragma unroll
        for (int f = 0; f < 4; f++)
#pragma unroll
            for (int r = 0; r < 4; r++) {
                float p = __builtin_amdgcn_exp2f((sf[f][r] - m_run) * LOG2E);
                sf[f][r] = p;
                psum += p;
            }
        l_part += psum;   // per-lane partial; reduced once in epilogue
        // packed redistribute: P (D-layout) -> PV a-frag layout
        unsigned pk[4][2];
#pragma unroll
        for (int f = 0; f < 4; f++)
#pragma unroll
            for (int hh2 = 0; hh2 < 2; hh2++)
                pk[f][hh2] = cvt_pk_bf16(sf[f][2 * hh2], sf[f][2 * hh2 + 1]);
        const int srcA = 32 * (g & 1) + s, srcB = srcA + 16;
        const bool ghi = g >= 2;
        us8 pa[2];
#pragma unroll
        for (int kk = 0; kk < 2; kk++) {
            unsigned e0 = __shfl(pk[kk * 2][0], srcA, 64);
            unsigned e1 = __shfl(pk[kk * 2][1], srcA, 64);
            unsigned e2 = __shfl(pk[kk * 2][0], srcB, 64);
            unsigned e3 = __shfl(pk[kk * 2][1], srcB, 64);
            unsigned o0 = __shfl(pk[kk * 2 + 1][0], srcA, 64);
            unsigned o1 = __shfl(pk[kk * 2 + 1][1], srcA, 64);
            unsigned o2 = __shfl(pk[kk * 2 + 1][0], srcB, 64);
            unsigned o3 = __shfl(pk[kk * 2 + 1][1], srcB, 64);
            u32x4 dw = { ghi ? o0 : e0, ghi ? o1 : e1, ghi ? o2 : e2, ghi ? o3 : e3 };
            pa[kk] = __builtin_bit_cast(us8, dw);
        }
        // PV: O[q][d] += P * V
        __builtin_amdgcn_s_setprio(1);
#pragma unroll
        for (int db = 0; db < 4; db++) {
            const char* vrow = Vc + (db * 16 + s) * 128;
            us8 vf0 = *(const us8*)(vrow + ((g * 16) ^ swl));
            o_acc[db] = mfma16(pa[0], vf0, o_acc[db]);
            us8 vf1 = *(const us8*)(vrow + ((64 + g * 16) ^ swl));
            o_acc[db] = mfma16(pa[1], vf1, o_acc[db]);
        }
        __builtin_amdgcn_s_setprio(0);
        cur ^= 1;
    }
    ATTN_EPILOGUE(qbB, o_acc, l_part);
}

// ---------------- output projection: Ob x Wc_bf16^T + bc, XCD-tiled 64x128 ----------------
__global__ __launch_bounds__(256) void gemm_out(
    const unsigned short* __restrict__ O, const unsigned short* __restrict__ Wcb,
    const float* __restrict__ bc, float* __restrict__ out) {
    __shared__ unsigned short As[64 * 72];
    __shared__ unsigned short Bs[128 * 72];
    const int bid = blockIdx.x;
    const int xcd = bid & 7, idx = bid >> 3;     // idx 0..63
    const int bm = xcd * 8 + (idx & 7);          // 0..63
    const int bn = idx >> 3;                     // 0..7
    const int m0 = bm * 64, n0 = bn * 128;
    f32x4 acc[2][4];
    gemm_core_bb<2>(O, Wcb, 1024, m0, n0, As, Bs, acc);
    const int lane = threadIdx.x & 63, wid = threadIdx.x >> 6;
    const int g = lane >> 4, s = lane & 15, wr = wid >> 1, wc = wid & 1;
#pragma unroll
    for (int mi = 0; mi < 2; mi++)
#pragma unroll
        for (int ni = 0; ni < 4; ni++) {
            int ng = n0 + wc * 64 + ni * 16 + s;
            float bias = bc[ng];
#pragma unroll
            for (int r = 0; r < 4; r++) {
                int mg = m0 + wr * 32 + mi * 16 + 4 * g + r;
                out[(size_t)mg * 1024 + ng] = acc[mi][ni][r] + bias;
            }
        }
}

extern "C" void kernel_launch(void* const* d_in, const int* in_sizes, int n_in,
                              void* d_out, int out_size, void* d_ws, size_t ws_size,
                              hipStream_t stream) {
    const float* x  = (const float*)d_in[0];
    const float* Wq = (const float*)d_in[1];
    const float* Wk = (const float*)d_in[2];
    const float* Wv = (const float*)d_in[3];
    const float* Wc = (const float*)d_in[4];
    const float* bc = (const float*)d_in[5];
    float* out = (float*)d_out;

    if (ws_size < 33554432) {
        fill_sentinel<<<(out_size + 255) / 256, 256, 0, stream>>>(out, out_size);
        return;
    }
    char* w = (char*)d_ws;
    unsigned short* Qb  = (unsigned short*)(w);
    unsigned short* Kb  = (unsigned short*)(w + 8388608);
    unsigned short* VtG = (unsigned short*)(w + 16777216);   // [bh][d][t]
    unsigned short* Ob  = (unsigned short*)(w + 25165824);
    unsigned short* Wcb = (unsigned short*)(w);              // reuses Qb region after attn
    unsigned short* xb    = (unsigned short*)d_out;
    unsigned short* wqkvb = (unsigned short*)((char*)d_out + 8388608);

    cvt_xw<<<7168, 256, 0, stream>>>(x, Wq, Wk, Wv, xb, wqkvb);
    gemm_qkv<<<768, 256, 0, stream>>>(xb, wqkvb, Qb, Kb, VtG);
    attn<<<512, 256, 0, stream>>>(Qb, Kb, VtG, Ob);
    cvt_wc<<<1024, 256, 0, stream>>>(Wc, Wcb);
    gemm_out<<<512, 256, 0, stream>>>(Ob, Wcb, bc, out);
}

// Round 20
// 116.089 us; speedup vs baseline: 1.0240x; 1.0168x over previous
//
#include <hip/hip_runtime.h>
#include <hip/hip_bf16.h>

// Fused MHA: B=2, T=2048, C=1024, H=16, dh=64.  (R17 + base-2 softmax domain)
// cvt_xw -> qkv GEMM (both-bf16 reg-staged, XCD-tiled; V transposed via LDS epilogue;
//    Q pre-scaled by 0.125*log2e -> scores in log2 units, exp2 without mul)
// -> flash attention (512 uniform paired blocks, XCD-local, 1-barrier dbuf,
//    XOR-swizzled [64][64] K/V LDS, per-lane defer-max thr 8*log2e)
// -> cvt_wc -> out GEMM (both-bf16, XCD-tiled).
// ws (32 MiB): Qb | Kb | VtG | Ob; Wc_bf16 reuses Qb region after attn.
// d_out scratch: xb [0,8MB) + wqkvb [8,14MB), dead before gemm_out writes out.

typedef __attribute__((ext_vector_type(4))) float f32x4;
typedef __attribute__((ext_vector_type(4))) unsigned int u32x4;
typedef __attribute__((ext_vector_type(8))) __bf16 bf16x8;
typedef __attribute__((ext_vector_type(8))) unsigned short us8;
typedef __attribute__((ext_vector_type(4))) unsigned short us4;

#define QSCALE 0.18033688011112042f   // 0.125 * log2(e): scores land in log2 units
#define DEFER_THR 11.541560327111708f // 8 * log2(e): P bounded by e^8 as before

__device__ __forceinline__ unsigned short f2bf(float f) {
    unsigned u = __builtin_bit_cast(unsigned, f);
    u += 0x7fffu + ((u >> 16) & 1u);   // round-to-nearest-even
    return (unsigned short)(u >> 16);
}

__device__ __forceinline__ unsigned cvt_pk_bf16(float lo, float hi) {
    unsigned r;
    asm("v_cvt_pk_bf16_f32 %0, %1, %2" : "=v"(r) : "v"(lo), "v"(hi));
    return r;
}

__device__ __forceinline__ f32x4 mfma16(us8 a, us8 b, f32x4 c) {
    return __builtin_amdgcn_mfma_f32_16x16x32_bf16(
        __builtin_bit_cast(bf16x8, a), __builtin_bit_cast(bf16x8, b), c, 0, 0, 0);
}

__global__ __launch_bounds__(256) void fill_sentinel(float* __restrict__ out, int n) {
    int i = blockIdx.x * 256 + threadIdx.x;
    if (i < n) out[i] = 12345.0f;
}

// ---- convert x + Wq|Wk|Wv fp32 -> bf16. 7168 blocks x 256 x 4.
__global__ __launch_bounds__(256) void cvt_xw(
    const float* __restrict__ x, const float* __restrict__ wq,
    const float* __restrict__ wk, const float* __restrict__ wv,
    unsigned short* __restrict__ xb, unsigned short* __restrict__ wqkvb) {
    long i = (long)(blockIdx.x * 256 + threadIdx.x) * 4;
    const float* src; unsigned short* dst; long off;
    if (i < 4194304L)      { src = x;  dst = xb;              off = i; }
    else if (i < 5242880L) { src = wq; dst = wqkvb;           off = i - 4194304L; }
    else if (i < 6291456L) { src = wk; dst = wqkvb + 1048576; off = i - 5242880L; }
    else                   { src = wv; dst = wqkvb + 2097152; off = i - 6291456L; }
    f32x4 v = *(const f32x4*)(src + off);
    us4 o = { f2bf(v[0]), f2bf(v[1]), f2bf(v[2]), f2bf(v[3]) };
    *(us4*)(dst + off) = o;
}

__global__ __launch_bounds__(256) void cvt_wc(const float* __restrict__ wc,
                                              unsigned short* __restrict__ wcb) {
    int idx = (blockIdx.x * 256 + threadIdx.x) * 4;
    f32x4 v = *(const f32x4*)(wc + idx);
    us4 o = { f2bf(v[0]), f2bf(v[1]), f2bf(v[2]), f2bf(v[3]) };
    *(us4*)(wcb + idx) = o;
}

// ---------------- both-bf16 reg-staged GEMM core ----------------
template <int MI>
__device__ __forceinline__ void gemm_core_bb(
    const unsigned short* __restrict__ A, const unsigned short* __restrict__ B,
    int K, int m0, int n0, unsigned short* As, unsigned short* Bs, f32x4 acc[MI][4]) {
    const int tid = threadIdx.x;
    const int lane = tid & 63, wid = tid >> 6;
    const int g = lane >> 4, s = lane & 15;
    const int wr = wid >> 1, wc = wid & 1;
#pragma unroll
    for (int mi = 0; mi < MI; mi++)
#pragma unroll
        for (int ni = 0; ni < 4; ni++) acc[mi][ni] = (f32x4){0.f, 0.f, 0.f, 0.f};
    const int row = tid >> 3, col = (tid & 7) * 8;
    for (int k0 = 0; k0 < K; k0 += 64) {
        us8 av[MI], bv[4];
#pragma unroll
        for (int p = 0; p < MI; p++)
            av[p] = *(const us8*)(A + (size_t)(m0 + row + p * 32) * K + k0 + col);
#pragma unroll
        for (int p = 0; p < 4; p++)
            bv[p] = *(const us8*)(B + (size_t)(n0 + row + p * 32) * K + k0 + col);
        __syncthreads();
#pragma unroll
        for (int p = 0; p < MI; p++)
            *(us8*)(As + (row + p * 32) * 72 + col) = av[p];
#pragma unroll
        for (int p = 0; p < 4; p++)
            *(us8*)(Bs + (row + p * 32) * 72 + col) = bv[p];
        __syncthreads();
#pragma unroll
        for (int kk = 0; kk < 2; kk++) {
            us8 af[MI], bf[4];
#pragma unroll
            for (int mi = 0; mi < MI; mi++)
                af[mi] = *(const us8*)(As + (wr * (MI * 16) + mi * 16 + s) * 72 + kk * 32 + g * 8);
#pragma unroll
            for (int ni = 0; ni < 4; ni++)
                bf[ni] = *(const us8*)(Bs + (wc * 64 + ni * 16 + s) * 72 + kk * 32 + g * 8);
#pragma unroll
            for (int mi = 0; mi < MI; mi++)
#pragma unroll
                for (int ni = 0; ni < 4; ni++)
                    acc[mi][ni] = mfma16(af[mi], bf[ni], acc[mi][ni]);
        }
    }
}

// ---------------- QKV projection (XCD-tiled); V transposed via LDS epilogue ----------------
__global__ __launch_bounds__(256) void gemm_qkv(
    const unsigned short* __restrict__ X, const unsigned short* __restrict__ Wb,
    unsigned short* __restrict__ Qb, unsigned short* __restrict__ Kb,
    unsigned short* __restrict__ VtG) {
    __shared__ unsigned short S[18432];   // As[128*72] | Bs[128*72]; V reuse: T[128][136]=17408
    unsigned short* As = S;
    unsigned short* Bs = S + 9216;
    const int bid = blockIdx.x;
    const int xcd = bid & 7, idx = bid >> 3;               // idx 0..95
    const int bm  = (xcd & 3) * 8 + (idx & 7);             // 0..31
    const int bnl = (xcd >> 2) * 12 + (idx >> 3);          // 0..23
    const int m0 = bm * 128;
    const int which = bnl >> 3;                            // 0:Q 1:K 2:V
    const int n0 = (bnl & 7) * 128;
    const unsigned short* W = Wb + (size_t)which * 1048576;
    f32x4 acc[4][4];
    gemm_core_bb<4>(X, W, 1024, m0, n0, As, Bs, acc);
    const int tid = threadIdx.x, lane = tid & 63, wid = tid >> 6;
    const int g = lane >> 4, s = lane & 15, wr = wid >> 1, wc = wid & 1;
    if (which < 2) {
        unsigned short* dst = which == 0 ? Qb : Kb;
        const float scale = which == 0 ? QSCALE : 1.0f;   // Q carries 1/sqrt(dh) * log2e
#pragma unroll
        for (int mi = 0; mi < 4; mi++)
#pragma unroll
            for (int ni = 0; ni < 4; ni++) {
                int n1 = n0 + wc * 64 + ni * 16 + s;
                int hh = n1 >> 6, dd = n1 & 63;
#pragma unroll
                for (int r = 0; r < 4; r++) {
                    int mg = m0 + wr * 64 + mi * 16 + 4 * g + r;
                    int bb = mg >> 11, tt = mg & 2047;
                    dst[((size_t)(bb * 16 + hh) * 2048 + tt) * 64 + dd] = f2bf(acc[mi][ni][r] * scale);
                }
            }
    } else {
        __syncthreads();
        unsigned* T32 = (unsigned*)S;   // T[128][136] shorts = [128][68] dwords
#pragma unroll
        for (int mi = 0; mi < 4; mi++)
#pragma unroll
            for (int ni = 0; ni < 4; ni++) {
                int nl = wc * 64 + ni * 16 + s;
                int mlh = ((wr * 64 + mi * 16) >> 1) + 2 * g;
                T32[nl * 68 + mlh]     = cvt_pk_bf16(acc[mi][ni][0], acc[mi][ni][1]);
                T32[nl * 68 + mlh + 1] = cvt_pk_bf16(acc[mi][ni][2], acc[mi][ni][3]);
            }
        __syncthreads();
        const int row = tid >> 4, col8 = (tid & 15) * 8;
        const int bb = m0 >> 11, tt0 = m0 & 2047;
#pragma unroll
        for (int p = 0; p < 8; p++) {
            int nl = row + 16 * p;
            int n1 = n0 + nl, hh = n1 >> 6, dd = n1 & 63;
            us8 v = *(const us8*)(S + nl * 136 + col8);
            *(us8*)(VtG + ((size_t)(bb * 16 + hh) * 64 + dd) * 2048 + tt0 + col8) = v;
        }
    }
}

// ---------------- flash attention (causal), 512 uniform paired blocks, XCD-local ----------------
// bh = bid&31, i = bid>>5 (0..15). Tile A=i (iters 0..i) then B=31-i: 33 iters/block.
// Scores arrive in log2 units (Q pre-scaled) -> exp2 without per-value mul.
// K/V LDS: unpadded [64][64], XOR swizzle byte ^= (row&7)<<4 (conflict-free).
// Per-lane defer-max thr 8*log2e; l per-lane, reduced in epilogue. 1-barrier dbuf.
#define ATTN_EPILOGUE(QB0, OA, LP)                                              \
    {                                                                           \
        float lf = (LP);                                                        \
        lf += __shfl_xor(lf, 16);                                               \
        lf += __shfl_xor(lf, 32);                                               \
        float li[4];                                                            \
        _Pragma("unroll") for (int r = 0; r < 4; r++)                           \
            li[r] = __shfl(lf, 4 * g + r, 64);                                  \
        _Pragma("unroll") for (int db = 0; db < 4; db++)                        \
            _Pragma("unroll") for (int r = 0; r < 4; r++) {                     \
                int qq = (QB0) + 4 * g + r;                                     \
                float v = (OA)[db][r] / li[r];                                  \
                Ob[((size_t)(b * 2048) + qq) * 1024 + h * 64 + db * 16 + s] = f2bf(v); \
            }                                                                   \
    }

__global__ __launch_bounds__(256) void attn(
    const unsigned short* __restrict__ Qb, const unsigned short* __restrict__ Kb,
    const unsigned short* __restrict__ VtG, unsigned short* __restrict__ Ob) {
    __shared__ unsigned short Ks[2][64 * 64];  // [k][d], XOR-swizzled
    __shared__ unsigned short Vt[2][64 * 64];  // [d][k], XOR-swizzled
    const int bh = blockIdx.x & 31, i = blockIdx.x >> 5;   // i in 0..15
    const int b = bh >> 4, h = bh & 15;
    const unsigned short* Qp = Qb + (size_t)bh * 2048 * 64;
    const unsigned short* Kp = Kb + (size_t)bh * 2048 * 64;
    const unsigned short* Vp = VtG + (size_t)bh * 64 * 2048;   // [d][t]
    const int tid = threadIdx.x, lane = tid & 63, wid = tid >> 6;
    const int g = lane >> 4, s = lane & 15;
    const int qbA = i * 64 + wid * 16;          // tile A
    const int qbB = (31 - i) * 64 + wid * 16;   // tile B
    const int qgA = qbA + s, qgB = qbB + s;
    us8 qfA[2], qfB[2];
    qfA[0] = *(const us8*)(Qp + (size_t)qgA * 64 + g * 8);
    qfA[1] = *(const us8*)(Qp + (size_t)qgA * 64 + 32 + g * 8);
    qfB[0] = *(const us8*)(Qp + (size_t)qgB * 64 + g * 8);
    qfB[1] = *(const us8*)(Qp + (size_t)qgB * 64 + 32 + g * 8);
    float m_run = -3.0e38f, l_part = 0.f;
    f32x4 o_acc[4];
#pragma unroll
    for (int db = 0; db < 4; db++) o_acc[db] = (f32x4){0.f, 0.f, 0.f, 0.f};
    const int srow = tid >> 3;                 // 0..31
    const int scolb = (tid & 7) * 16;          // byte col within 128B row
    const int swl = (s & 7) << 4;              // read-side XOR (row&7 == s&7)
    auto tileoff = [&](int jj) { return (jj <= i ? jj : jj - i - 1) * 64; };
    us8 kpre[2], vpre[2];
    // stage tile 0 directly (swizzled write: byte = row*128 + (colb ^ ((row&7)<<4)))
#pragma unroll
    for (int p = 0; p < 2; p++) {
        kpre[p] = *(const us8*)((const char*)Kp + (size_t)(srow + 32 * p) * 128 + scolb);
        vpre[p] = *(const us8*)((const char*)Vp + (size_t)(srow + 32 * p) * 4096 + scolb);
    }
#pragma unroll
    for (int p = 0; p < 2; p++) {
        int row = srow + 32 * p;
        int sw = scolb ^ ((row & 7) << 4);
        *(us8*)((char*)&Ks[0][0] + row * 128 + sw) = kpre[p];
        *(us8*)((char*)&Vt[0][0] + row * 128 + sw) = vpre[p];
    }
    {   // prefetch tile 1
        const int nk = tileoff(1);
#pragma unroll
        for (int p = 0; p < 2; p++) {
            kpre[p] = *(const us8*)((const char*)Kp + (size_t)(nk + srow + 32 * p) * 128 + scolb);
            vpre[p] = *(const us8*)((const char*)Vp + (size_t)(srow + 32 * p) * 4096 + nk * 2 + scolb);
        }
    }
    int cur = 0;
    for (int it = 0; it <= 32; ++it) {
        __syncthreads();   // buf[cur] writes visible; prior reads of buf[cur^1] done
        if (it < 32) {     // stage tile it+1 into the other buffer
#pragma unroll
            for (int p = 0; p < 2; p++) {
                int row = srow + 32 * p;
                int sw = scolb ^ ((row & 7) << 4);
                *(us8*)((char*)&Ks[cur ^ 1][0] + row * 128 + sw) = kpre[p];
                *(us8*)((char*)&Vt[cur ^ 1][0] + row * 128 + sw) = vpre[p];
            }
            if (it < 31) {   // prefetch tile it+2
                const int nk = tileoff(it + 2);
#pragma unroll
                for (int p = 0; p < 2; p++) {
                    kpre[p] = *(const us8*)((const char*)Kp + (size_t)(nk + srow + 32 * p) * 128 + scolb);
                    vpre[p] = *(const us8*)((const char*)Vp + (size_t)(srow + 32 * p) * 4096 + nk * 2 + scolb);
                }
            }
        }
        if (it == i + 1) {   // tile A finished: emit + reset stats
            ATTN_EPILOGUE(qbA, o_acc, l_part);
            m_run = -3.0e38f; l_part = 0.f;
#pragma unroll
            for (int db = 0; db < 4; db++) o_acc[db] = (f32x4){0.f, 0.f, 0.f, 0.f};
        }
        const bool qsel = it > i;
        const int kv0 = tileoff(it);
        const int qg = qsel ? qgB : qgA;
        const us8* qf = qsel ? qfB : qfA;
        const char* Kc = (const char*)&Ks[cur][0];
        const char* Vc = (const char*)&Vt[cur][0];
        float sf[4][4];
        __builtin_amdgcn_s_setprio(1);
#pragma unroll
        for (int f = 0; f < 4; f++) {
            f32x4 a = (f32x4){0.f, 0.f, 0.f, 0.f};
            const char* krow = Kc + (f * 16 + s) * 128;
            us8 k0v = *(const us8*)(krow + ((g * 16) ^ swl));
            us8 k1v = *(const us8*)(krow + ((64 + g * 16) ^ swl));
            a = mfma16(k0v, qf[0], a);
            a = mfma16(k1v, qf[1], a);
#pragma unroll
            for (int r = 0; r < 4; r++) sf[f][r] = a[r];
        }
        __builtin_amdgcn_s_setprio(0);
        const bool diag = qsel ? (it == 32) : (it == i);
        if (diag) {   // diagonal tile: mask k > q
#pragma unroll
            for (int f = 0; f < 4; f++)
#pragma unroll
                for (int r = 0; r < 4; r++)
                    if (kv0 + f * 16 + 4 * g + r > qg) sf[f][r] = -3.0e38f;
        }
        // per-lane defer-max (log2 units)
        float mt = -3.0e38f;
#pragma unroll
        for (int f = 0; f < 4; f++)
#pragma unroll
            for (int r = 0; r < 4; r++) mt = fmaxf(mt, sf[f][r]);
        if (!__all(mt - m_run <= DEFER_THR)) {   // rare: reduce + rescale
            mt = fmaxf(mt, __shfl_xor(mt, 16));
            mt = fmaxf(mt, __shfl_xor(mt, 32));
            float mnew = fmaxf(m_run, mt);
            float alpha = __builtin_amdgcn_exp2f(m_run - mnew);
            l_part *= alpha;
            float al[4];
#pragma unroll
            for (int r = 0; r < 4; r++) al[r] = __shfl(alpha, 4 * g + r, 64);
#pragma unroll
            for (int db = 0; db < 4; db++)
#pragma unroll
                for (int r = 0; r < 4; r++) o_acc[db][r] *= al[r];
            m_run = mnew;
        }
        float psum = 0.f;
#pragma unroll
        for (int f = 0; f < 4; f++)
#pragma unroll
            for (int r = 0; r < 4; r++) {
                float p = __builtin_amdgcn_exp2f(sf[f][r] - m_run);
                sf[f][r] = p;
                psum += p;
            }
        l_part += psum;   // per-lane partial; reduced once in epilogue
        // packed redistribute: P (D-layout) -> PV a-frag layout
        unsigned pk[4][2];
#pragma unroll
        for (int f = 0; f < 4; f++)
#pragma unroll
            for (int hh2 = 0; hh2 < 2; hh2++)
                pk[f][hh2] = cvt_pk_bf16(sf[f][2 * hh2], sf[f][2 * hh2 + 1]);
        const int srcA = 32 * (g & 1) + s, srcB = srcA + 16;
        const bool ghi = g >= 2;
        us8 pa[2];
#pragma unroll
        for (int kk = 0; kk < 2; kk++) {
            unsigned e0 = __shfl(pk[kk * 2][0], srcA, 64);
            unsigned e1 = __shfl(pk[kk * 2][1], srcA, 64);
            unsigned e2 = __shfl(pk[kk * 2][0], srcB, 64);
            unsigned e3 = __shfl(pk[kk * 2][1], srcB, 64);
            unsigned o0 = __shfl(pk[kk * 2 + 1][0], srcA, 64);
            unsigned o1 = __shfl(pk[kk * 2 + 1][1], srcA, 64);
            unsigned o2 = __shfl(pk[kk * 2 + 1][0], srcB, 64);
            unsigned o3 = __shfl(pk[kk * 2 + 1][1], srcB, 64);
            u32x4 dw = { ghi ? o0 : e0, ghi ? o1 : e1, ghi ? o2 : e2, ghi ? o3 : e3 };
            pa[kk] = __builtin_bit_cast(us8, dw);
        }
        // PV: O[q][d] += P * V
        __builtin_amdgcn_s_setprio(1);
#pragma unroll
        for (int db = 0; db < 4; db++) {
            const char* vrow = Vc + (db * 16 + s) * 128;
            us8 vf0 = *(const us8*)(vrow + ((g * 16) ^ swl));
            o_acc[db] = mfma16(pa[0], vf0, o_acc[db]);
            us8 vf1 = *(const us8*)(vrow + ((64 + g * 16) ^ swl));
            o_acc[db] = mfma16(pa[1], vf1, o_acc[db]);
        }
        __builtin_amdgcn_s_setprio(0);
        cur ^= 1;
    }
    ATTN_EPILOGUE(qbB, o_acc, l_part);
}

// ---------------- output projection: Ob x Wc_bf16^T + bc, XCD-tiled 64x128 ----------------
__global__ __launch_bounds__(256) void gemm_out(
    const unsigned short* __restrict__ O, const unsigned short* __restrict__ Wcb,
    const float* __restrict__ bc, float* __restrict__ out) {
    __shared__ unsigned short As[64 * 72];
    __shared__ unsigned short Bs[128 * 72];
    const int bid = blockIdx.x;
    const int xcd = bid & 7, idx = bid >> 3;     // idx 0..63
    const int bm = xcd * 8 + (idx & 7);          // 0..63
    const int bn = idx >> 3;                     // 0..7
    const int m0 = bm * 64, n0 = bn * 128;
    f32x4 acc[2][4];
    gemm_core_bb<2>(O, Wcb, 1024, m0, n0, As, Bs, acc);
    const int lane = threadIdx.x & 63, wid = threadIdx.x >> 6;
    const int g = lane >> 4, s = lane & 15, wr = wid >> 1, wc = wid & 1;
#pragma unroll
    for (int mi = 0; mi < 2; mi++)
#pragma unroll
        for (int ni = 0; ni < 4; ni++) {
            int ng = n0 + wc * 64 + ni * 16 + s;
            float bias = bc[ng];
#pragma unroll
            for (int r = 0; r < 4; r++) {
                int mg = m0 + wr * 32 + mi * 16 + 4 * g + r;
                out[(size_t)mg * 1024 + ng] = acc[mi][ni][r] + bias;
            }
        }
}

extern "C" void kernel_launch(void* const* d_in, const int* in_sizes, int n_in,
                              void* d_out, int out_size, void* d_ws, size_t ws_size,
                              hipStream_t stream) {
    const float* x  = (const float*)d_in[0];
    const float* Wq = (const float*)d_in[1];
    const float* Wk = (const float*)d_in[2];
    const float* Wv = (const float*)d_in[3];
    const float* Wc = (const float*)d_in[4];
    const float* bc = (const float*)d_in[5];
    float* out = (float*)d_out;

    if (ws_size < 33554432) {
        fill_sentinel<<<(out_size + 255) / 256, 256, 0, stream>>>(out, out_size);
        return;
    }
    char* w = (char*)d_ws;
    unsigned short* Qb  = (unsigned short*)(w);
    unsigned short* Kb  = (unsigned short*)(w + 8388608);
    unsigned short* VtG = (unsigned short*)(w + 16777216);   // [bh][d][t]
    unsigned short* Ob  = (unsigned short*)(w + 25165824);
    unsigned short* Wcb = (unsigned short*)(w);              // reuses Qb region after attn
    unsigned short* xb    = (unsigned short*)d_out;
    unsigned short* wqkvb = (unsigned short*)((char*)d_out + 8388608);

    cvt_xw<<<7168, 256, 0, stream>>>(x, Wq, Wk, Wv, xb, wqkvb);
    gemm_qkv<<<768, 256, 0, stream>>>(xb, wqkvb, Qb, Kb, VtG);
    attn<<<512, 256, 0, stream>>>(Qb, Kb, VtG, Ob);
    cvt_wc<<<1024, 256, 0, stream>>>(Wc, Wcb);
    gemm_out<<<512, 256, 0, stream>>>(Ob, Wcb, bc, out);
}

// Round 21
// 115.696 us; speedup vs baseline: 1.0274x; 1.0034x over previous
//
#include <hip/hip_runtime.h>
#include <hip/hip_bf16.h>

// Fused MHA: B=2, T=2048, C=1024, H=16, dh=64.  (R20 + epilogue reciprocal)
// cvt_xw -> qkv GEMM (both-bf16 reg-staged, XCD-tiled; V transposed via LDS epilogue;
//    Q pre-scaled by 0.125*log2e -> scores in log2 units, exp2 without mul)
// -> flash attention (512 uniform paired blocks, XCD-local, 1-barrier dbuf,
//    XOR-swizzled [64][64] K/V LDS, per-lane defer-max thr 8*log2e)
// -> cvt_wc -> out GEMM (both-bf16, XCD-tiled).
// ws (32 MiB): Qb | Kb | VtG | Ob; Wc_bf16 reuses Qb region after attn.
// d_out scratch: xb [0,8MB) + wqkvb [8,14MB), dead before gemm_out writes out.

typedef __attribute__((ext_vector_type(4))) float f32x4;
typedef __attribute__((ext_vector_type(4))) unsigned int u32x4;
typedef __attribute__((ext_vector_type(8))) __bf16 bf16x8;
typedef __attribute__((ext_vector_type(8))) unsigned short us8;
typedef __attribute__((ext_vector_type(4))) unsigned short us4;

#define QSCALE 0.18033688011112042f   // 0.125 * log2(e): scores land in log2 units
#define DEFER_THR 11.541560327111708f // 8 * log2(e): P bounded by e^8 as before

__device__ __forceinline__ unsigned short f2bf(float f) {
    unsigned u = __builtin_bit_cast(unsigned, f);
    u += 0x7fffu + ((u >> 16) & 1u);   // round-to-nearest-even
    return (unsigned short)(u >> 16);
}

__device__ __forceinline__ unsigned cvt_pk_bf16(float lo, float hi) {
    unsigned r;
    asm("v_cvt_pk_bf16_f32 %0, %1, %2" : "=v"(r) : "v"(lo), "v"(hi));
    return r;
}

__device__ __forceinline__ f32x4 mfma16(us8 a, us8 b, f32x4 c) {
    return __builtin_amdgcn_mfma_f32_16x16x32_bf16(
        __builtin_bit_cast(bf16x8, a), __builtin_bit_cast(bf16x8, b), c, 0, 0, 0);
}

__global__ __launch_bounds__(256) void fill_sentinel(float* __restrict__ out, int n) {
    int i = blockIdx.x * 256 + threadIdx.x;
    if (i < n) out[i] = 12345.0f;
}

// ---- convert x + Wq|Wk|Wv fp32 -> bf16. 7168 blocks x 256 x 4.
__global__ __launch_bounds__(256) void cvt_xw(
    const float* __restrict__ x, const float* __restrict__ wq,
    const float* __restrict__ wk, const float* __restrict__ wv,
    unsigned short* __restrict__ xb, unsigned short* __restrict__ wqkvb) {
    long i = (long)(blockIdx.x * 256 + threadIdx.x) * 4;
    const float* src; unsigned short* dst; long off;
    if (i < 4194304L)      { src = x;  dst = xb;              off = i; }
    else if (i < 5242880L) { src = wq; dst = wqkvb;           off = i - 4194304L; }
    else if (i < 6291456L) { src = wk; dst = wqkvb + 1048576; off = i - 5242880L; }
    else                   { src = wv; dst = wqkvb + 2097152; off = i - 6291456L; }
    f32x4 v = *(const f32x4*)(src + off);
    us4 o = { f2bf(v[0]), f2bf(v[1]), f2bf(v[2]), f2bf(v[3]) };
    *(us4*)(dst + off) = o;
}

__global__ __launch_bounds__(256) void cvt_wc(const float* __restrict__ wc,
                                              unsigned short* __restrict__ wcb) {
    int idx = (blockIdx.x * 256 + threadIdx.x) * 4;
    f32x4 v = *(const f32x4*)(wc + idx);
    us4 o = { f2bf(v[0]), f2bf(v[1]), f2bf(v[2]), f2bf(v[3]) };
    *(us4*)(wcb + idx) = o;
}

// ---------------- both-bf16 reg-staged GEMM core ----------------
template <int MI>
__device__ __forceinline__ void gemm_core_bb(
    const unsigned short* __restrict__ A, const unsigned short* __restrict__ B,
    int K, int m0, int n0, unsigned short* As, unsigned short* Bs, f32x4 acc[MI][4]) {
    const int tid = threadIdx.x;
    const int lane = tid & 63, wid = tid >> 6;
    const int g = lane >> 4, s = lane & 15;
    const int wr = wid >> 1, wc = wid & 1;
#pragma unroll
    for (int mi = 0; mi < MI; mi++)
#pragma unroll
        for (int ni = 0; ni < 4; ni++) acc[mi][ni] = (f32x4){0.f, 0.f, 0.f, 0.f};
    const int row = tid >> 3, col = (tid & 7) * 8;
    for (int k0 = 0; k0 < K; k0 += 64) {
        us8 av[MI], bv[4];
#pragma unroll
        for (int p = 0; p < MI; p++)
            av[p] = *(const us8*)(A + (size_t)(m0 + row + p * 32) * K + k0 + col);
#pragma unroll
        for (int p = 0; p < 4; p++)
            bv[p] = *(const us8*)(B + (size_t)(n0 + row + p * 32) * K + k0 + col);
        __syncthreads();
#pragma unroll
        for (int p = 0; p < MI; p++)
            *(us8*)(As + (row + p * 32) * 72 + col) = av[p];
#pragma unroll
        for (int p = 0; p < 4; p++)
            *(us8*)(Bs + (row + p * 32) * 72 + col) = bv[p];
        __syncthreads();
#pragma unroll
        for (int kk = 0; kk < 2; kk++) {
            us8 af[MI], bf[4];
#pragma unroll
            for (int mi = 0; mi < MI; mi++)
                af[mi] = *(const us8*)(As + (wr * (MI * 16) + mi * 16 + s) * 72 + kk * 32 + g * 8);
#pragma unroll
            for (int ni = 0; ni < 4; ni++)
                bf[ni] = *(const us8*)(Bs + (wc * 64 + ni * 16 + s) * 72 + kk * 32 + g * 8);
#pragma unroll
            for (int mi = 0; mi < MI; mi++)
#pragma unroll
                for (int ni = 0; ni < 4; ni++)
                    acc[mi][ni] = mfma16(af[mi], bf[ni], acc[mi][ni]);
        }
    }
}

// ---------------- QKV projection (XCD-tiled); V transposed via LDS epilogue ----------------
__global__ __launch_bounds__(256) void gemm_qkv(
    const unsigned short* __restrict__ X, const unsigned short* __restrict__ Wb,
    unsigned short* __restrict__ Qb, unsigned short* __restrict__ Kb,
    unsigned short* __restrict__ VtG) {
    __shared__ unsigned short S[18432];   // As[128*72] | Bs[128*72]; V reuse: T[128][136]=17408
    unsigned short* As = S;
    unsigned short* Bs = S + 9216;
    const int bid = blockIdx.x;
    const int xcd = bid & 7, idx = bid >> 3;               // idx 0..95
    const int bm  = (xcd & 3) * 8 + (idx & 7);             // 0..31
    const int bnl = (xcd >> 2) * 12 + (idx >> 3);          // 0..23
    const int m0 = bm * 128;
    const int which = bnl >> 3;                            // 0:Q 1:K 2:V
    const int n0 = (bnl & 7) * 128;
    const unsigned short* W = Wb + (size_t)which * 1048576;
    f32x4 acc[4][4];
    gemm_core_bb<4>(X, W, 1024, m0, n0, As, Bs, acc);
    const int tid = threadIdx.x, lane = tid & 63, wid = tid >> 6;
    const int g = lane >> 4, s = lane & 15, wr = wid >> 1, wc = wid & 1;
    if (which < 2) {
        unsigned short* dst = which == 0 ? Qb : Kb;
        const float scale = which == 0 ? QSCALE : 1.0f;   // Q carries 1/sqrt(dh) * log2e
#pragma unroll
        for (int mi = 0; mi < 4; mi++)
#pragma unroll
            for (int ni = 0; ni < 4; ni++) {
                int n1 = n0 + wc * 64 + ni * 16 + s;
                int hh = n1 >> 6, dd = n1 & 63;
#pragma unroll
                for (int r = 0; r < 4; r++) {
                    int mg = m0 + wr * 64 + mi * 16 + 4 * g + r;
                    int bb = mg >> 11, tt = mg & 2047;
                    dst[((size_t)(bb * 16 + hh) * 2048 + tt) * 64 + dd] = f2bf(acc[mi][ni][r] * scale);
                }
            }
    } else {
        __syncthreads();
        unsigned* T32 = (unsigned*)S;   // T[128][136] shorts = [128][68] dwords
#pragma unroll
        for (int mi = 0; mi < 4; mi++)
#pragma unroll
            for (int ni = 0; ni < 4; ni++) {
                int nl = wc * 64 + ni * 16 + s;
                int mlh = ((wr * 64 + mi * 16) >> 1) + 2 * g;
                T32[nl * 68 + mlh]     = cvt_pk_bf16(acc[mi][ni][0], acc[mi][ni][1]);
                T32[nl * 68 + mlh + 1] = cvt_pk_bf16(acc[mi][ni][2], acc[mi][ni][3]);
            }
        __syncthreads();
        const int row = tid >> 4, col8 = (tid & 15) * 8;
        const int bb = m0 >> 11, tt0 = m0 & 2047;
#pragma unroll
        for (int p = 0; p < 8; p++) {
            int nl = row + 16 * p;
            int n1 = n0 + nl, hh = n1 >> 6, dd = n1 & 63;
            us8 v = *(const us8*)(S + nl * 136 + col8);
            *(us8*)(VtG + ((size_t)(bb * 16 + hh) * 64 + dd) * 2048 + tt0 + col8) = v;
        }
    }
}

// ---------------- flash attention (causal), 512 uniform paired blocks, XCD-local ----------------
// bh = bid&31, i = bid>>5 (0..15). Tile A=i (iters 0..i) then B=31-i: 33 iters/block.
// Scores in log2 units (Q pre-scaled) -> exp2 without per-value mul.
// K/V LDS: unpadded [64][64], XOR swizzle byte ^= (row&7)<<4 (conflict-free).
// Per-lane defer-max thr 8*log2e; l per-lane, reduced + ONE rcp in epilogue.
#define ATTN_EPILOGUE(QB0, OA, LP)                                              \
    {                                                                           \
        float lf = (LP);                                                        \
        lf += __shfl_xor(lf, 16);                                               \
        lf += __shfl_xor(lf, 32);                                               \
        float lr = 1.0f / lf;   /* one divide; 16 muls below */                 \
        float li[4];                                                            \
        _Pragma("unroll") for (int r = 0; r < 4; r++)                           \
            li[r] = __shfl(lr, 4 * g + r, 64);                                  \
        _Pragma("unroll") for (int db = 0; db < 4; db++)                        \
            _Pragma("unroll") for (int r = 0; r < 4; r++) {                     \
                int qq = (QB0) + 4 * g + r;                                     \
                float v = (OA)[db][r] * li[r];                                  \
                Ob[((size_t)(b * 2048) + qq) * 1024 + h * 64 + db * 16 + s] = f2bf(v); \
            }                                                                   \
    }

__global__ __launch_bounds__(256) void attn(
    const unsigned short* __restrict__ Qb, const unsigned short* __restrict__ Kb,
    const unsigned short* __restrict__ VtG, unsigned short* __restrict__ Ob) {
    __shared__ unsigned short Ks[2][64 * 64];  // [k][d], XOR-swizzled
    __shared__ unsigned short Vt[2][64 * 64];  // [d][k], XOR-swizzled
    const int bh = blockIdx.x & 31, i = blockIdx.x >> 5;   // i in 0..15
    const int b = bh >> 4, h = bh & 15;
    const unsigned short* Qp = Qb + (size_t)bh * 2048 * 64;
    const unsigned short* Kp = Kb + (size_t)bh * 2048 * 64;
    const unsigned short* Vp = VtG + (size_t)bh * 64 * 2048;   // [d][t]
    const int tid = threadIdx.x, lane = tid & 63, wid = tid >> 6;
    const int g = lane >> 4, s = lane & 15;
    const int qbA = i * 64 + wid * 16;          // tile A
    const int qbB = (31 - i) * 64 + wid * 16;   // tile B
    const int qgA = qbA + s, qgB = qbB + s;
    us8 qfA[2], qfB[2];
    qfA[0] = *(const us8*)(Qp + (size_t)qgA * 64 + g * 8);
    qfA[1] = *(const us8*)(Qp + (size_t)qgA * 64 + 32 + g * 8);
    qfB[0] = *(const us8*)(Qp + (size_t)qgB * 64 + g * 8);
    qfB[1] = *(const us8*)(Qp + (size_t)qgB * 64 + 32 + g * 8);
    float m_run = -3.0e38f, l_part = 0.f;
    f32x4 o_acc[4];
#pragma unroll
    for (int db = 0; db < 4; db++) o_acc[db] = (f32x4){0.f, 0.f, 0.f, 0.f};
    const int srow = tid >> 3;                 // 0..31
    const int scolb = (tid & 7) * 16;          // byte col within 128B row
    const int swl = (s & 7) << 4;              // read-side XOR (row&7 == s&7)
    auto tileoff = [&](int jj) { return (jj <= i ? jj : jj - i - 1) * 64; };
    us8 kpre[2], vpre[2];
    // stage tile 0 directly (swizzled write: byte = row*128 + (colb ^ ((row&7)<<4)))
#pragma unroll
    for (int p = 0; p < 2; p++) {
        kpre[p] = *(const us8*)((const char*)Kp + (size_t)(srow + 32 * p) * 128 + scolb);
        vpre[p] = *(const us8*)((const char*)Vp + (size_t)(srow + 32 * p) * 4096 + scolb);
    }
#pragma unroll
    for (int p = 0; p < 2; p++) {
        int row = srow + 32 * p;
        int sw = scolb ^ ((row & 7) << 4);
        *(us8*)((char*)&Ks[0][0] + row * 128 + sw) = kpre[p];
        *(us8*)((char*)&Vt[0][0] + row * 128 + sw) = vpre[p];
    }
    {   // prefetch tile 1
        const int nk = tileoff(1);
#pragma unroll
        for (int p = 0; p < 2; p++) {
            kpre[p] = *(const us8*)((const char*)Kp + (size_t)(nk + srow + 32 * p) * 128 + scolb);
            vpre[p] = *(const us8*)((const char*)Vp + (size_t)(srow + 32 * p) * 4096 + nk * 2 + scolb);
        }
    }
    int cur = 0;
    for (int it = 0; it <= 32; ++it) {
        __syncthreads();   // buf[cur] writes visible; prior reads of buf[cur^1] done
        if (it < 32) {     // stage tile it+1 into the other buffer
#pragma unroll
            for (int p = 0; p < 2; p++) {
                int row = srow + 32 * p;
                int sw = scolb ^ ((row & 7) << 4);
                *(us8*)((char*)&Ks[cur ^ 1][0] + row * 128 + sw) = kpre[p];
                *(us8*)((char*)&Vt[cur ^ 1][0] + row * 128 + sw) = vpre[p];
            }
            if (it < 31) {   // prefetch tile it+2
                const int nk = tileoff(it + 2);
#pragma unroll
                for (int p = 0; p < 2; p++) {
                    kpre[p] = *(const us8*)((const char*)Kp + (size_t)(nk + srow + 32 * p) * 128 + scolb);
                    vpre[p] = *(const us8*)((const char*)Vp + (size_t)(srow + 32 * p) * 4096 + nk * 2 + scolb);
                }
            }
        }
        if (it == i + 1) {   // tile A finished: emit + reset stats
            ATTN_EPILOGUE(qbA, o_acc, l_part);
            m_run = -3.0e38f; l_part = 0.f;
#pragma unroll
            for (int db = 0; db < 4; db++) o_acc[db] = (f32x4){0.f, 0.f, 0.f, 0.f};
        }
        const bool qsel = it > i;
        const int kv0 = tileoff(it);
        const int qg = qsel ? qgB : qgA;
        const us8* qf = qsel ? qfB : qfA;
        const char* Kc = (const char*)&Ks[cur][0];
        const char* Vc = (const char*)&Vt[cur][0];
        float sf[4][4];
        __builtin_amdgcn_s_setprio(1);
#pragma unroll
        for (int f = 0; f < 4; f++) {
            f32x4 a = (f32x4){0.f, 0.f, 0.f, 0.f};
            const char* krow = Kc + (f * 16 + s) * 128;
            us8 k0v = *(const us8*)(krow + ((g * 16) ^ swl));
            us8 k1v = *(const us8*)(krow + ((64 + g * 16) ^ swl));
            a = mfma16(k0v, qf[0], a);
            a = mfma16(k1v, qf[1], a);
#pragma unroll
            for (int r = 0; r < 4; r++) sf[f][r] = a[r];
        }
        __builtin_amdgcn_s_setprio(0);
        const bool diag = qsel ? (it == 32) : (it == i);
        if (diag) {   // diagonal tile: mask k > q
#pragma unroll
            for (int f = 0; f < 4; f++)
#pragma unroll
                for (int r = 0; r < 4; r++)
                    if (kv0 + f * 16 + 4 * g + r > qg) sf[f][r] = -3.0e38f;
        }
        // per-lane defer-max (log2 units)
        float mt = -3.0e38f;
#pragma unroll
        for (int f = 0; f < 4; f++)
#pragma unroll
            for (int r = 0; r < 4; r++) mt = fmaxf(mt, sf[f][r]);
        if (!__all(mt - m_run <= DEFER_THR)) {   // rare: reduce + rescale
            mt = fmaxf(mt, __shfl_xor(mt, 16));
            mt = fmaxf(mt, __shfl_xor(mt, 32));
            float mnew = fmaxf(m_run, mt);
            float alpha = __builtin_amdgcn_exp2f(m_run - mnew);
            l_part *= alpha;
            float al[4];
#pragma unroll
            for (int r = 0; r < 4; r++) al[r] = __shfl(alpha, 4 * g + r, 64);
#pragma unroll
            for (int db = 0; db < 4; db++)
#pragma unroll
                for (int r = 0; r < 4; r++) o_acc[db][r] *= al[r];
            m_run = mnew;
        }
        float psum = 0.f;
#pragma unroll
        for (int f = 0; f < 4; f++)
#pragma unroll
            for (int r = 0; r < 4; r++) {
                float p = __builtin_amdgcn_exp2f(sf[f][r] - m_run);
                sf[f][r] = p;
                psum += p;
            }
        l_part += psum;   // per-lane partial; reduced once in epilogue
        // packed redistribute: P (D-layout) -> PV a-frag layout
        unsigned pk[4][2];
#pragma unroll
        for (int f = 0; f < 4; f++)
#pragma unroll
            for (int hh2 = 0; hh2 < 2; hh2++)
                pk[f][hh2] = cvt_pk_bf16(sf[f][2 * hh2], sf[f][2 * hh2 + 1]);
        const int srcA = 32 * (g & 1) + s, srcB = srcA + 16;
        const bool ghi = g >= 2;
        us8 pa[2];
#pragma unroll
        for (int kk = 0; kk < 2; kk++) {
            unsigned e0 = __shfl(pk[kk * 2][0], srcA, 64);
            unsigned e1 = __shfl(pk[kk * 2][1], srcA, 64);
            unsigned e2 = __shfl(pk[kk * 2][0], srcB, 64);
            unsigned e3 = __shfl(pk[kk * 2][1], srcB, 64);
            unsigned o0 = __shfl(pk[kk * 2 + 1][0], srcA, 64);
            unsigned o1 = __shfl(pk[kk * 2 + 1][1], srcA, 64);
            unsigned o2 = __shfl(pk[kk * 2 + 1][0], srcB, 64);
            unsigned o3 = __shfl(pk[kk * 2 + 1][1], srcB, 64);
            u32x4 dw = { ghi ? o0 : e0, ghi ? o1 : e1, ghi ? o2 : e2, ghi ? o3 : e3 };
            pa[kk] = __builtin_bit_cast(us8, dw);
        }
        // PV: O[q][d] += P * V
        __builtin_amdgcn_s_setprio(1);
#pragma unroll
        for (int db = 0; db < 4; db++) {
            const char* vrow = Vc + (db * 16 + s) * 128;
            us8 vf0 = *(const us8*)(vrow + ((g * 16) ^ swl));
            o_acc[db] = mfma16(pa[0], vf0, o_acc[db]);
            us8 vf1 = *(const us8*)(vrow + ((64 + g * 16) ^ swl));
            o_acc[db] = mfma16(pa[1], vf1, o_acc[db]);
        }
        __builtin_amdgcn_s_setprio(0);
        cur ^= 1;
    }
    ATTN_EPILOGUE(qbB, o_acc, l_part);
}

// ---------------- output projection: Ob x Wc_bf16^T + bc, XCD-tiled 64x128 ----------------
__global__ __launch_bounds__(256) void gemm_out(
    const unsigned short* __restrict__ O, const unsigned short* __restrict__ Wcb,
    const float* __restrict__ bc, float* __restrict__ out) {
    __shared__ unsigned short As[64 * 72];
    __shared__ unsigned short Bs[128 * 72];
    const int bid = blockIdx.x;
    const int xcd = bid & 7, idx = bid >> 3;     // idx 0..63
    const int bm = xcd * 8 + (idx & 7);          // 0..63
    const int bn = idx >> 3;                     // 0..7
    const int m0 = bm * 64, n0 = bn * 128;
    f32x4 acc[2][4];
    gemm_core_bb<2>(O, Wcb, 1024, m0, n0, As, Bs, acc);
    const int lane = threadIdx.x & 63, wid = threadIdx.x >> 6;
    const int g = lane >> 4, s = lane & 15, wr = wid >> 1, wc = wid & 1;
#pragma unroll
    for (int mi = 0; mi < 2; mi++)
#pragma unroll
        for (int ni = 0; ni < 4; ni++) {
            int ng = n0 + wc * 64 + ni * 16 + s;
            float bias = bc[ng];
#pragma unroll
            for (int r = 0; r < 4; r++) {
                int mg = m0 + wr * 32 + mi * 16 + 4 * g + r;
                out[(size_t)mg * 1024 + ng] = acc[mi][ni][r] + bias;
            }
        }
}

extern "C" void kernel_launch(void* const* d_in, const int* in_sizes, int n_in,
                              void* d_out, int out_size, void* d_ws, size_t ws_size,
                              hipStream_t stream) {
    const float* x  = (const float*)d_in[0];
    const float* Wq = (const float*)d_in[1];
    const float* Wk = (const float*)d_in[2];
    const float* Wv = (const float*)d_in[3];
    const float* Wc = (const float*)d_in[4];
    const float* bc = (const float*)d_in[5];
    float* out = (float*)d_out;

    if (ws_size < 33554432) {
        fill_sentinel<<<(out_size + 255) / 256, 256, 0, stream>>>(out, out_size);
        return;
    }
    char* w = (char*)d_ws;
    unsigned short* Qb  = (unsigned short*)(w);
    unsigned short* Kb  = (unsigned short*)(w + 8388608);
    unsigned short* VtG = (unsigned short*)(w + 16777216);   // [bh][d][t]
    unsigned short* Ob  = (unsigned short*)(w + 25165824);
    unsigned short* Wcb = (unsigned short*)(w);              // reuses Qb region after attn
    unsigned short* xb    = (unsigned short*)d_out;
    unsigned short* wqkvb = (unsigned short*)((char*)d_out + 8388608);

    cvt_xw<<<7168, 256, 0, stream>>>(x, Wq, Wk, Wv, xb, wqkvb);
    gemm_qkv<<<768, 256, 0, stream>>>(xb, wqkvb, Qb, Kb, VtG);
    attn<<<512, 256, 0, stream>>>(Qb, Kb, VtG, Ob);
    cvt_wc<<<1024, 256, 0, stream>>>(Wc, Wcb);
    gemm_out<<<512, 256, 0, stream>>>(Ob, Wcb, bc, out);
}

// Round 23
// 115.279 us; speedup vs baseline: 1.0312x; 1.0036x over previous
//
#include <hip/hip_runtime.h>
#include <hip/hip_bf16.h>

// Fused MHA: B=2, T=2048, C=1024, H=16, dh=64.  (R21 final configuration)
// cvt_xw -> qkv GEMM (both-bf16 reg-staged, XCD-tiled; V transposed via LDS epilogue;
//    Q pre-scaled by 0.125*log2e -> scores in log2 units, exp2 without mul)
// -> flash attention (512 uniform paired blocks, XCD-local, 1-barrier dbuf,
//    XOR-swizzled [64][64] K/V LDS, per-lane defer-max thr 8*log2e)
// -> cvt_wc -> out GEMM (both-bf16, XCD-tiled).
// ws (32 MiB): Qb | Kb | VtG | Ob; Wc_bf16 reuses Qb region after attn.
// d_out scratch: xb [0,8MB) + wqkvb [8,14MB), dead before gemm_out writes out.

typedef __attribute__((ext_vector_type(4))) float f32x4;
typedef __attribute__((ext_vector_type(4))) unsigned int u32x4;
typedef __attribute__((ext_vector_type(8))) __bf16 bf16x8;
typedef __attribute__((ext_vector_type(8))) unsigned short us8;
typedef __attribute__((ext_vector_type(4))) unsigned short us4;

#define QSCALE 0.18033688011112042f   // 0.125 * log2(e): scores land in log2 units
#define DEFER_THR 11.541560327111708f // 8 * log2(e): P bounded by e^8 as before

__device__ __forceinline__ unsigned short f2bf(float f) {
    unsigned u = __builtin_bit_cast(unsigned, f);
    u += 0x7fffu + ((u >> 16) & 1u);   // round-to-nearest-even
    return (unsigned short)(u >> 16);
}

__device__ __forceinline__ unsigned cvt_pk_bf16(float lo, float hi) {
    unsigned r;
    asm("v_cvt_pk_bf16_f32 %0, %1, %2" : "=v"(r) : "v"(lo), "v"(hi));
    return r;
}

__device__ __forceinline__ f32x4 mfma16(us8 a, us8 b, f32x4 c) {
    return __builtin_amdgcn_mfma_f32_16x16x32_bf16(
        __builtin_bit_cast(bf16x8, a), __builtin_bit_cast(bf16x8, b), c, 0, 0, 0);
}

__global__ __launch_bounds__(256) void fill_sentinel(float* __restrict__ out, int n) {
    int i = blockIdx.x * 256 + threadIdx.x;
    if (i < n) out[i] = 12345.0f;
}

// ---- convert x + Wq|Wk|Wv fp32 -> bf16. 7168 blocks x 256 x 4.
__global__ __launch_bounds__(256) void cvt_xw(
    const float* __restrict__ x, const float* __restrict__ wq,
    const float* __restrict__ wk, const float* __restrict__ wv,
    unsigned short* __restrict__ xb, unsigned short* __restrict__ wqkvb) {
    long i = (long)(blockIdx.x * 256 + threadIdx.x) * 4;
    const float* src; unsigned short* dst; long off;
    if (i < 4194304L)      { src = x;  dst = xb;              off = i; }
    else if (i < 5242880L) { src = wq; dst = wqkvb;           off = i - 4194304L; }
    else if (i < 6291456L) { src = wk; dst = wqkvb + 1048576; off = i - 5242880L; }
    else                   { src = wv; dst = wqkvb + 2097152; off = i - 6291456L; }
    f32x4 v = *(const f32x4*)(src + off);
    us4 o = { f2bf(v[0]), f2bf(v[1]), f2bf(v[2]), f2bf(v[3]) };
    *(us4*)(dst + off) = o;
}

__global__ __launch_bounds__(256) void cvt_wc(const float* __restrict__ wc,
                                              unsigned short* __restrict__ wcb) {
    int idx = (blockIdx.x * 256 + threadIdx.x) * 4;
    f32x4 v = *(const f32x4*)(wc + idx);
    us4 o = { f2bf(v[0]), f2bf(v[1]), f2bf(v[2]), f2bf(v[3]) };
    *(us4*)(wcb + idx) = o;
}

// ---------------- both-bf16 reg-staged GEMM core ----------------
template <int MI>
__device__ __forceinline__ void gemm_core_bb(
    const unsigned short* __restrict__ A, const unsigned short* __restrict__ B,
    int K, int m0, int n0, unsigned short* As, unsigned short* Bs, f32x4 acc[MI][4]) {
    const int tid = threadIdx.x;
    const int lane = tid & 63, wid = tid >> 6;
    const int g = lane >> 4, s = lane & 15;
    const int wr = wid >> 1, wc = wid & 1;
#pragma unroll
    for (int mi = 0; mi < MI; mi++)
#pragma unroll
        for (int ni = 0; ni < 4; ni++) acc[mi][ni] = (f32x4){0.f, 0.f, 0.f, 0.f};
    const int row = tid >> 3, col = (tid & 7) * 8;
    for (int k0 = 0; k0 < K; k0 += 64) {
        us8 av[MI], bv[4];
#pragma unroll
        for (int p = 0; p < MI; p++)
            av[p] = *(const us8*)(A + (size_t)(m0 + row + p * 32) * K + k0 + col);
#pragma unroll
        for (int p = 0; p < 4; p++)
            bv[p] = *(const us8*)(B + (size_t)(n0 + row + p * 32) * K + k0 + col);
        __syncthreads();
#pragma unroll
        for (int p = 0; p < MI; p++)
            *(us8*)(As + (row + p * 32) * 72 + col) = av[p];
#pragma unroll
        for (int p = 0; p < 4; p++)
            *(us8*)(Bs + (row + p * 32) * 72 + col) = bv[p];
        __syncthreads();
#pragma unroll
        for (int kk = 0; kk < 2; kk++) {
            us8 af[MI], bf[4];
#pragma unroll
            for (int mi = 0; mi < MI; mi++)
                af[mi] = *(const us8*)(As + (wr * (MI * 16) + mi * 16 + s) * 72 + kk * 32 + g * 8);
#pragma unroll
            for (int ni = 0; ni < 4; ni++)
                bf[ni] = *(const us8*)(Bs + (wc * 64 + ni * 16 + s) * 72 + kk * 32 + g * 8);
#pragma unroll
            for (int mi = 0; mi < MI; mi++)
#pragma unroll
                for (int ni = 0; ni < 4; ni++)
                    acc[mi][ni] = mfma16(af[mi], bf[ni], acc[mi][ni]);
        }
    }
}

// ---------------- QKV projection (XCD-tiled); V transposed via LDS epilogue ----------------
__global__ __launch_bounds__(256) void gemm_qkv(
    const unsigned short* __restrict__ X, const unsigned short* __restrict__ Wb,
    unsigned short* __restrict__ Qb, unsigned short* __restrict__ Kb,
    unsigned short* __restrict__ VtG) {
    __shared__ unsigned short S[18432];   // As[128*72] | Bs[128*72]; V reuse: T[128][136]=17408
    unsigned short* As = S;
    unsigned short* Bs = S + 9216;
    const int bid = blockIdx.x;
    const int xcd = bid & 7, idx = bid >> 3;               // idx 0..95
    const int bm  = (xcd & 3) * 8 + (idx & 7);             // 0..31
    const int bnl = (xcd >> 2) * 12 + (idx >> 3);          // 0..23
    const int m0 = bm * 128;
    const int which = bnl >> 3;                            // 0:Q 1:K 2:V
    const int n0 = (bnl & 7) * 128;
    const unsigned short* W = Wb + (size_t)which * 1048576;
    f32x4 acc[4][4];
    gemm_core_bb<4>(X, W, 1024, m0, n0, As, Bs, acc);
    const int tid = threadIdx.x, lane = tid & 63, wid = tid >> 6;
    const int g = lane >> 4, s = lane & 15, wr = wid >> 1, wc = wid & 1;
    if (which < 2) {
        unsigned short* dst = which == 0 ? Qb : Kb;
        const float scale = which == 0 ? QSCALE : 1.0f;   // Q carries 1/sqrt(dh) * log2e
#pragma unroll
        for (int mi = 0; mi < 4; mi++)
#pragma unroll
            for (int ni = 0; ni < 4; ni++) {
                int n1 = n0 + wc * 64 + ni * 16 + s;
                int hh = n1 >> 6, dd = n1 & 63;
#pragma unroll
                for (int r = 0; r < 4; r++) {
                    int mg = m0 + wr * 64 + mi * 16 + 4 * g + r;
                    int bb = mg >> 11, tt = mg & 2047;
                    dst[((size_t)(bb * 16 + hh) * 2048 + tt) * 64 + dd] = f2bf(acc[mi][ni][r] * scale);
                }
            }
    } else {
        __syncthreads();
        unsigned* T32 = (unsigned*)S;   // T[128][136] shorts = [128][68] dwords
#pragma unroll
        for (int mi = 0; mi < 4; mi++)
#pragma unroll
            for (int ni = 0; ni < 4; ni++) {
                int nl = wc * 64 + ni * 16 + s;
                int mlh = ((wr * 64 + mi * 16) >> 1) + 2 * g;
                T32[nl * 68 + mlh]     = cvt_pk_bf16(acc[mi][ni][0], acc[mi][ni][1]);
                T32[nl * 68 + mlh + 1] = cvt_pk_bf16(acc[mi][ni][2], acc[mi][ni][3]);
            }
        __syncthreads();
        const int row = tid >> 4, col8 = (tid & 15) * 8;
        const int bb = m0 >> 11, tt0 = m0 & 2047;
#pragma unroll
        for (int p = 0; p < 8; p++) {
            int nl = row + 16 * p;
            int n1 = n0 + nl, hh = n1 >> 6, dd = n1 & 63;
            us8 v = *(const us8*)(S + nl * 136 + col8);
            *(us8*)(VtG + ((size_t)(bb * 16 + hh) * 64 + dd) * 2048 + tt0 + col8) = v;
        }
    }
}

// ---------------- flash attention (causal), 512 uniform paired blocks, XCD-local ----------------
// bh = bid&31, i = bid>>5 (0..15). Tile A=i (iters 0..i) then B=31-i: 33 iters/block.
// Scores in log2 units (Q pre-scaled) -> exp2 without per-value mul.
// K/V LDS: unpadded [64][64], XOR swizzle byte ^= (row&7)<<4 (conflict-free).
// Per-lane defer-max thr 8*log2e; l per-lane, reduced + ONE rcp in epilogue.
#define ATTN_EPILOGUE(QB0, OA, LP)                                              \
    {                                                                           \
        float lf = (LP);                                                        \
        lf += __shfl_xor(lf, 16);                                               \
        lf += __shfl_xor(lf, 32);                                               \
        float lr = 1.0f / lf;   /* one divide; 16 muls below */                 \
        float li[4];                                                            \
        _Pragma("unroll") for (int r = 0; r < 4; r++)                           \
            li[r] = __shfl(lr, 4 * g + r, 64);                                  \
        _Pragma("unroll") for (int db = 0; db < 4; db++)                        \
            _Pragma("unroll") for (int r = 0; r < 4; r++) {                     \
                int qq = (QB0) + 4 * g + r;                                     \
                float v = (OA)[db][r] * li[r];                                  \
                Ob[((size_t)(b * 2048) + qq) * 1024 + h * 64 + db * 16 + s] = f2bf(v); \
            }                                                                   \
    }

__global__ __launch_bounds__(256) void attn(
    const unsigned short* __restrict__ Qb, const unsigned short* __restrict__ Kb,
    const unsigned short* __restrict__ VtG, unsigned short* __restrict__ Ob) {
    __shared__ unsigned short Ks[2][64 * 64];  // [k][d], XOR-swizzled
    __shared__ unsigned short Vt[2][64 * 64];  // [d][k], XOR-swizzled
    const int bh = blockIdx.x & 31, i = blockIdx.x >> 5;   // i in 0..15
    const int b = bh >> 4, h = bh & 15;
    const unsigned short* Qp = Qb + (size_t)bh * 2048 * 64;
    const unsigned short* Kp = Kb + (size_t)bh * 2048 * 64;
    const unsigned short* Vp = VtG + (size_t)bh * 64 * 2048;   // [d][t]
    const int tid = threadIdx.x, lane = tid & 63, wid = tid >> 6;
    const int g = lane >> 4, s = lane & 15;
    const int qbA = i * 64 + wid * 16;          // tile A
    const int qbB = (31 - i) * 64 + wid * 16;   // tile B
    const int qgA = qbA + s, qgB = qbB + s;
    us8 qfA[2], qfB[2];
    qfA[0] = *(const us8*)(Qp + (size_t)qgA * 64 + g * 8);
    qfA[1] = *(const us8*)(Qp + (size_t)qgA * 64 + 32 + g * 8);
    qfB[0] = *(const us8*)(Qp + (size_t)qgB * 64 + g * 8);
    qfB[1] = *(const us8*)(Qp + (size_t)qgB * 64 + 32 + g * 8);
    float m_run = -3.0e38f, l_part = 0.f;
    f32x4 o_acc[4];
#pragma unroll
    for (int db = 0; db < 4; db++) o_acc[db] = (f32x4){0.f, 0.f, 0.f, 0.f};
    const int srow = tid >> 3;                 // 0..31
    const int scolb = (tid & 7) * 16;          // byte col within 128B row
    const int swl = (s & 7) << 4;              // read-side XOR (row&7 == s&7)
    auto tileoff = [&](int jj) { return (jj <= i ? jj : jj - i - 1) * 64; };
    us8 kpre[2], vpre[2];
    // stage tile 0 directly (swizzled write: byte = row*128 + (colb ^ ((row&7)<<4)))
#pragma unroll
    for (int p = 0; p < 2; p++) {
        kpre[p] = *(const us8*)((const char*)Kp + (size_t)(srow + 32 * p) * 128 + scolb);
        vpre[p] = *(const us8*)((const char*)Vp + (size_t)(srow + 32 * p) * 4096 + scolb);
    }
#pragma unroll
    for (int p = 0; p < 2; p++) {
        int row = srow + 32 * p;
        int sw = scolb ^ ((row & 7) << 4);
        *(us8*)((char*)&Ks[0][0] + row * 128 + sw) = kpre[p];
        *(us8*)((char*)&Vt[0][0] + row * 128 + sw) = vpre[p];
    }
    {   // prefetch tile 1
        const int nk = tileoff(1);
#pragma unroll
        for (int p = 0; p < 2; p++) {
            kpre[p] = *(const us8*)((const char*)Kp + (size_t)(nk + srow + 32 * p) * 128 + scolb);
            vpre[p] = *(const us8*)((const char*)Vp + (size_t)(srow + 32 * p) * 4096 + nk * 2 + scolb);
        }
    }
    int cur = 0;
    for (int it = 0; it <= 32; ++it) {
        __syncthreads();   // buf[cur] writes visible; prior reads of buf[cur^1] done
        if (it < 32) {     // stage tile it+1 into the other buffer
#pragma unroll
            for (int p = 0; p < 2; p++) {
                int row = srow + 32 * p;
                int sw = scolb ^ ((row & 7) << 4);
                *(us8*)((char*)&Ks[cur ^ 1][0] + row * 128 + sw) = kpre[p];
                *(us8*)((char*)&Vt[cur ^ 1][0] + row * 128 + sw) = vpre[p];
            }
            if (it < 31) {   // prefetch tile it+2
                const int nk = tileoff(it + 2);
#pragma unroll
                for (int p = 0; p < 2; p++) {
                    kpre[p] = *(const us8*)((const char*)Kp + (size_t)(nk + srow + 32 * p) * 128 + scolb);
                    vpre[p] = *(const us8*)((const char*)Vp + (size_t)(srow + 32 * p) * 4096 + nk * 2 + scolb);
                }
            }
        }
        if (it == i + 1) {   // tile A finished: emit + reset stats
            ATTN_EPILOGUE(qbA, o_acc, l_part);
            m_run = -3.0e38f; l_part = 0.f;
#pragma unroll
            for (int db = 0; db < 4; db++) o_acc[db] = (f32x4){0.f, 0.f, 0.f, 0.f};
        }
        const bool qsel = it > i;
        const int kv0 = tileoff(it);
        const int qg = qsel ? qgB : qgA;
        const us8* qf = qsel ? qfB : qfA;
        const char* Kc = (const char*)&Ks[cur][0];
        const char* Vc = (const char*)&Vt[cur][0];
        float sf[4][4];
        __builtin_amdgcn_s_setprio(1);
#pragma unroll
        for (int f = 0; f < 4; f++) {
            f32x4 a = (f32x4){0.f, 0.f, 0.f, 0.f};
            const char* krow = Kc + (f * 16 + s) * 128;
            us8 k0v = *(const us8*)(krow + ((g * 16) ^ swl));
            us8 k1v = *(const us8*)(krow + ((64 + g * 16) ^ swl));
            a = mfma16(k0v, qf[0], a);
            a = mfma16(k1v, qf[1], a);
#pragma unroll
            for (int r = 0; r < 4; r++) sf[f][r] = a[r];
        }
        __builtin_amdgcn_s_setprio(0);
        const bool diag = qsel ? (it == 32) : (it == i);
        if (diag) {   // diagonal tile: mask k > q
#pragma unroll
            for (int f = 0; f < 4; f++)
#pragma unroll
                for (int r = 0; r < 4; r++)
                    if (kv0 + f * 16 + 4 * g + r > qg) sf[f][r] = -3.0e38f;
        }
        // per-lane defer-max (log2 units)
        float mt = -3.0e38f;
#pragma unroll
        for (int f = 0; f < 4; f++)
#pragma unroll
            for (int r = 0; r < 4; r++) mt = fmaxf(mt, sf[f][r]);
        if (!__all(mt - m_run <= DEFER_THR)) {   // rare: reduce + rescale
            mt = fmaxf(mt, __shfl_xor(mt, 16));
            mt = fmaxf(mt, __shfl_xor(mt, 32));
            float mnew = fmaxf(m_run, mt);
            float alpha = __builtin_amdgcn_exp2f(m_run - mnew);
            l_part *= alpha;
            float al[4];
#pragma unroll
            for (int r = 0; r < 4; r++) al[r] = __shfl(alpha, 4 * g + r, 64);
#pragma unroll
            for (int db = 0; db < 4; db++)
#pragma unroll
                for (int r = 0; r < 4; r++) o_acc[db][r] *= al[r];
            m_run = mnew;
        }
        float psum = 0.f;
#pragma unroll
        for (int f = 0; f < 4; f++)
#pragma unroll
            for (int r = 0; r < 4; r++) {
                float p = __builtin_amdgcn_exp2f(sf[f][r] - m_run);
                sf[f][r] = p;
                psum += p;
            }
        l_part += psum;   // per-lane partial; reduced once in epilogue
        // packed redistribute: P (D-layout) -> PV a-frag layout
        unsigned pk[4][2];
#pragma unroll
        for (int f = 0; f < 4; f++)
#pragma unroll
            for (int hh2 = 0; hh2 < 2; hh2++)
                pk[f][hh2] = cvt_pk_bf16(sf[f][2 * hh2], sf[f][2 * hh2 + 1]);
        const int srcA = 32 * (g & 1) + s, srcB = srcA + 16;
        const bool ghi = g >= 2;
        us8 pa[2];
#pragma unroll
        for (int kk = 0; kk < 2; kk++) {
            unsigned e0 = __shfl(pk[kk * 2][0], srcA, 64);
            unsigned e1 = __shfl(pk[kk * 2][1], srcA, 64);
            unsigned e2 = __shfl(pk[kk * 2][0], srcB, 64);
            unsigned e3 = __shfl(pk[kk * 2][1], srcB, 64);
            unsigned o0 = __shfl(pk[kk * 2 + 1][0], srcA, 64);
            unsigned o1 = __shfl(pk[kk * 2 + 1][1], srcA, 64);
            unsigned o2 = __shfl(pk[kk * 2 + 1][0], srcB, 64);
            unsigned o3 = __shfl(pk[kk * 2 + 1][1], srcB, 64);
            u32x4 dw = { ghi ? o0 : e0, ghi ? o1 : e1, ghi ? o2 : e2, ghi ? o3 : e3 };
            pa[kk] = __builtin_bit_cast(us8, dw);
        }
        // PV: O[q][d] += P * V
        __builtin_amdgcn_s_setprio(1);
#pragma unroll
        for (int db = 0; db < 4; db++) {
            const char* vrow = Vc + (db * 16 + s) * 128;
            us8 vf0 = *(const us8*)(vrow + ((g * 16) ^ swl));
            o_acc[db] = mfma16(pa[0], vf0, o_acc[db]);
            us8 vf1 = *(const us8*)(vrow + ((64 + g * 16) ^ swl));
            o_acc[db] = mfma16(pa[1], vf1, o_acc[db]);
        }
        __builtin_amdgcn_s_setprio(0);
        cur ^= 1;
    }
    ATTN_EPILOGUE(qbB, o_acc, l_part);
}

// ---------------- output projection: Ob x Wc_bf16^T + bc, XCD-tiled 64x128 ----------------
__global__ __launch_bounds__(256) void gemm_out(
    const unsigned short* __restrict__ O, const unsigned short* __restrict__ Wcb,
    const float* __restrict__ bc, float* __restrict__ out) {
    __shared__ unsigned short As[64 * 72];
    __shared__ unsigned short Bs[128 * 72];
    const int bid = blockIdx.x;
    const int xcd = bid & 7, idx = bid >> 3;     // idx 0..63
    const int bm = xcd * 8 + (idx & 7);          // 0..63
    const int bn = idx >> 3;                     // 0..7
    const int m0 = bm * 64, n0 = bn * 128;
    f32x4 acc[2][4];
    gemm_core_bb<2>(O, Wcb, 1024, m0, n0, As, Bs, acc);
    const int lane = threadIdx.x & 63, wid = threadIdx.x >> 6;
    const int g = lane >> 4, s = lane & 15, wr = wid >> 1, wc = wid & 1;
#pragma unroll
    for (int mi = 0; mi < 2; mi++)
#pragma unroll
        for (int ni = 0; ni < 4; ni++) {
            int ng = n0 + wc * 64 + ni * 16 + s;
            float bias = bc[ng];
#pragma unroll
            for (int r = 0; r < 4; r++) {
                int mg = m0 + wr * 32 + mi * 16 + 4 * g + r;
                out[(size_t)mg * 1024 + ng] = acc[mi][ni][r] + bias;
            }
        }
}

extern "C" void kernel_launch(void* const* d_in, const int* in_sizes, int n_in,
                              void* d_out, int out_size, void* d_ws, size_t ws_size,
                              hipStream_t stream) {
    const float* x  = (const float*)d_in[0];
    const float* Wq = (const float*)d_in[1];
    const float* Wk = (const float*)d_in[2];
    const float* Wv = (const float*)d_in[3];
    const float* Wc = (const float*)d_in[4];
    const float* bc = (const float*)d_in[5];
    float* out = (float*)d_out;

    if (ws_size < 33554432) {
        fill_sentinel<<<(out_size + 255) / 256, 256, 0, stream>>>(out, out_size);
        return;
    }
    char* w = (char*)d_ws;
    unsigned short* Qb  = (unsigned short*)(w);
    unsigned short* Kb  = (unsigned short*)(w + 8388608);
    unsigned short* VtG = (unsigned short*)(w + 16777216);   // [bh][d][t]
    unsigned short* Ob  = (unsigned short*)(w + 25165824);
    unsigned short* Wcb = (unsigned short*)(w);              // reuses Qb region after attn
    unsigned short* xb    = (unsigned short*)d_out;
    unsigned short* wqkvb = (unsigned short*)((char*)d_out + 8388608);

    cvt_xw<<<7168, 256, 0, stream>>>(x, Wq, Wk, Wv, xb, wqkvb);
    gemm_qkv<<<768, 256, 0, stream>>>(xb, wqkvb, Qb, Kb, VtG);
    attn<<<512, 256, 0, stream>>>(Qb, Kb, VtG, Ob);
    cvt_wc<<<1024, 256, 0, stream>>>(Wc, Wcb);
    gemm_out<<<512, 256, 0, stream>>>(Ob, Wcb, bc, out);
}